// Round 2
// baseline (1885.683 us; speedup 1.0000x reference)
//
#include <hip/hip_runtime.h>
#include <hip/hip_bf16.h>

#define NN 20000
#define NE 60000
#define NT 1024

typedef unsigned short ushortT;
typedef __attribute__((ext_vector_type(8))) short bf16x8;
typedef __attribute__((ext_vector_type(4))) float f32x4;

__device__ __forceinline__ float sigm(float x){ return 1.0f/(1.0f+expf(-x)); }
__device__ __forceinline__ float bfu2f(ushortT u){ return __uint_as_float(((unsigned)u)<<16); }
__device__ __forceinline__ ushortT f2bfu(float f){
  __hip_bfloat16 b = __float2bfloat16(f);
  return *reinterpret_cast<ushortT*>(&b);
}

// ---------------- lin0: out = relu(x @ W0.T + b0); h = out ----------------
__global__ void k_lin0(const float* __restrict__ x, const float* __restrict__ W0,
                       const float* __restrict__ b0, float* __restrict__ out,
                       float* __restrict__ h){
  int idx = blockIdx.x*256 + threadIdx.x;       // N*64 exact
  int n = idx >> 6, j = idx & 63;
  float a = b0[j] + x[n*3+0]*W0[j*3+0] + x[n*3+1]*W0[j*3+1] + x[n*3+2]*W0[j*3+2];
  a = fmaxf(a, 0.0f);
  out[idx] = a; h[idx] = a;
}

__global__ void k_deg(const int* __restrict__ dst, float* __restrict__ deg){
  int e = blockIdx.x*256 + threadIdx.x;
  if (e < NE) atomicAdd(&deg[dst[e]], 1.0f);
}
__global__ void k_invdeg(float* __restrict__ deg){
  int n = blockIdx.x*256 + threadIdx.x;
  if (n < NN) deg[n] = 1.0f/fmaxf(deg[n], 1.0f);
}

// ------------- edge MLP hidden: R = relu(edge_attr @ We1.T + be1) (bf16) ----
__global__ void k_edgemlp(const float* __restrict__ ea, const float* __restrict__ We1,
                          const float* __restrict__ be1, ushortT* __restrict__ Rbf){
  int idx = blockIdx.x*256 + threadIdx.x;       // E*128 exact
  int e = idx >> 7, k = idx & 127;
  float a = be1[k];
  #pragma unroll
  for (int j = 0; j < 7; ++j) a += ea[e*7+j]*We1[k*7+j];
  Rbf[idx] = f2bfu(fmaxf(a, 0.0f));
}

// f32 -> bf16 copy (same layout)
__global__ void k_cvt(const float* __restrict__ in, ushortT* __restrict__ outp, int nelem){
  int idx = blockIdx.x*256 + threadIdx.x;
  if (idx < nelem) outp[idx] = f2bfu(in[idx]);
}

// generic transpose: in [R,C] -> out [C,R]
__global__ void k_tr(const float* __restrict__ in, float* __restrict__ out, int R, int C){
  int idx = blockIdx.x*256 + threadIdx.x;
  if (idx < R*C){ int r = idx / C, c = idx % C; out[c*R + r] = in[idx]; }
}

// ---------- fused NNConv message: agg[dst[e]] += out[src[e]] @ (R[e]@We2^T + be2) ----------
// Block: 256 thr (4 waves), EB=128 edges. Wave w owns edges [w*32, w*32+32) (2 row-tiles).
// GEMM D[e][c] = sum_k R[e][k]*We2[c][k] via mfma 16x16x32 bf16; consume each tile:
// msg[e][f] += o_s[e][c>>6] * (D[e][c] + be2[c]),  f = c & 63.
#define EB 128
__global__ __launch_bounds__(256) void k_fmsg(
    const ushortT* __restrict__ Rbf, const ushortT* __restrict__ We2bf,
    const float* __restrict__ be2, const float* __restrict__ out,
    const int* __restrict__ src, const int* __restrict__ dst,
    float* __restrict__ agg)
{
  __shared__ float o_s[EB][68];     // gathered out[src[e]], padded rows
  __shared__ int   dst_s[EB];
  int tid = threadIdx.x;
  int e0 = blockIdx.x * EB;

  // gather o_s: thread -> edge ei = tid>>1, half = (tid&1)*32
  {
    int ei = tid >> 1, half = (tid & 1) * 32;
    int ge = e0 + ei;
    int sn = (ge < NE) ? src[ge] : 0;
    const float* op = out + (size_t)sn*64 + half;
    #pragma unroll
    for (int i = 0; i < 8; ++i){
      float4 v = (ge < NE) ? *reinterpret_cast<const float4*>(op + i*4)
                           : make_float4(0.f,0.f,0.f,0.f);
      *reinterpret_cast<float4*>(&o_s[ei][half + i*4]) = v;
    }
    if (tid < EB){
      int g2 = e0 + tid;
      dst_s[tid] = (g2 < NE) ? dst[g2] : -1;
    }
  }
  __syncthreads();

  int w = tid >> 6, l = tid & 63;
  int g = l >> 4, l15 = l & 15;

  // A fragments: R rows for this wave's 32 edges, all K=128 (4 k-steps)
  bf16x8 af0[4], af1[4];
  #pragma unroll
  for (int ks = 0; ks < 4; ++ks){
    int ge0 = e0 + w*32 + l15;
    int ge1 = ge0 + 16;
    bf16x8 z = {0,0,0,0,0,0,0,0};
    af0[ks] = (ge0 < NE) ? *reinterpret_cast<const bf16x8*>(Rbf + (size_t)ge0*128 + ks*32 + g*8) : z;
    af1[ks] = (ge1 < NE) ? *reinterpret_cast<const bf16x8*>(Rbf + (size_t)ge1*128 + ks*32 + g*8) : z;
  }

  float msg0[4][4] = {};   // [r][q]  e = w*32 + g*4 + r,      f = l15 + q*16
  float msg1[4][4] = {};   // [r][q]  e = w*32 + 16 + g*4 + r

  for (int d = 0; d < 64; ++d){
    float ov0[4], ov1[4];
    #pragma unroll
    for (int r = 0; r < 4; ++r){
      ov0[r] = o_s[w*32 + g*4 + r][d];
      ov1[r] = o_s[w*32 + 16 + g*4 + r][d];
    }
    #pragma unroll
    for (int q = 0; q < 4; ++q){
      int c0 = d*64 + q*16;
      const ushortT* bp = We2bf + (size_t)(c0 + l15)*128 + g*8;
      f32x4 ac0 = {0.f,0.f,0.f,0.f}, ac1 = {0.f,0.f,0.f,0.f};
      #pragma unroll
      for (int ks = 0; ks < 4; ++ks){
        bf16x8 bf = *reinterpret_cast<const bf16x8*>(bp + ks*32);
        ac0 = __builtin_amdgcn_mfma_f32_16x16x32_bf16(af0[ks], bf, ac0, 0, 0, 0);
        ac1 = __builtin_amdgcn_mfma_f32_16x16x32_bf16(af1[ks], bf, ac1, 0, 0, 0);
      }
      float be2v = be2[c0 + l15];
      #pragma unroll
      for (int r = 0; r < 4; ++r){
        msg0[r][q] += ov0[r]*(ac0[r] + be2v);
        msg1[r][q] += ov1[r]*(ac1[r] + be2v);
      }
    }
  }

  #pragma unroll
  for (int r = 0; r < 4; ++r){
    int el0 = w*32 + g*4 + r, el1 = el0 + 16;
    int t0 = dst_s[el0], t1 = dst_s[el1];
    #pragma unroll
    for (int q = 0; q < 4; ++q){
      if (t0 >= 0) atomicAdd(&agg[(size_t)t0*64 + q*16 + l15], msg0[r][q]);
      if (t1 >= 0) atomicAdd(&agg[(size_t)t1*64 + q*16 + l15], msg1[r][q]);
    }
  }
}

// ------------- NNConv epilogue + GRU cell (16 nodes / block, 4 per thread) ----------------
__global__ void k_gru(const float* __restrict__ agg, const float* __restrict__ inv_deg,
                      const float* __restrict__ root, const float* __restrict__ conv_b,
                      const float* __restrict__ wih_t, const float* __restrict__ whh_t,
                      const float* __restrict__ bih, const float* __restrict__ bhh,
                      float* __restrict__ out, float* __restrict__ h){
  __shared__ float os[16][64], hsm[16][64], ms[16][64];
  int tid = threadIdx.x;
  int j = tid & 63, sub = tid >> 6;   // sub 0..3
  int n0 = blockIdx.x * 16;
  #pragma unroll
  for (int i = 0; i < 4; ++i){
    int nl = sub + 4*i;
    os[nl][j]  = out[(size_t)(n0+nl)*64 + j];
    hsm[nl][j] = h[(size_t)(n0+nl)*64 + j];
  }
  __syncthreads();
  float a[4];
  #pragma unroll
  for (int i = 0; i < 4; ++i){
    int nl = sub + 4*i;
    a[i] = agg[(size_t)(n0+nl)*64 + j]*inv_deg[n0+nl] + conv_b[j];
  }
  for (int d = 0; d < 64; ++d){
    float rdj = root[d*64 + j];
    #pragma unroll
    for (int i = 0; i < 4; ++i) a[i] += os[sub + 4*i][d]*rdj;
  }
  #pragma unroll
  for (int i = 0; i < 4; ++i) ms[sub + 4*i][j] = fmaxf(a[i], 0.0f);
  __syncthreads();
  float gxr[4], gxz[4], gxn[4], ghr[4], ghz[4], ghn[4];
  #pragma unroll
  for (int i = 0; i < 4; ++i){
    gxr[i] = bih[j];     gxz[i] = bih[64+j];  gxn[i] = bih[128+j];
    ghr[i] = bhh[j];     ghz[i] = bhh[64+j];  ghn[i] = bhh[128+j];
  }
  for (int d = 0; d < 64; ++d){
    float wir = wih_t[d*192 + j], wiz = wih_t[d*192 + 64 + j], win = wih_t[d*192 + 128 + j];
    float whr = whh_t[d*192 + j], whz = whh_t[d*192 + 64 + j], whn = whh_t[d*192 + 128 + j];
    #pragma unroll
    for (int i = 0; i < 4; ++i){
      float mv = ms[sub + 4*i][d], hv = hsm[sub + 4*i][d];
      gxr[i] += mv*wir; gxz[i] += mv*wiz; gxn[i] += mv*win;
      ghr[i] += hv*whr; ghz[i] += hv*whz; ghn[i] += hv*whn;
    }
  }
  #pragma unroll
  for (int i = 0; i < 4; ++i){
    int nl = sub + 4*i;
    float r = sigm(gxr[i]+ghr[i]), zg = sigm(gxz[i]+ghz[i]);
    float nn_ = tanhf(gxn[i] + r*ghn[i]);
    float hn = (1.0f - zg)*nn_ + zg*hsm[nl][j];
    h[(size_t)(n0+nl)*64 + j]   = hn;
    out[(size_t)(n0+nl)*64 + j] = hn;
  }
}

// ------------- Set2Set -------------
// st layout (floats): hs[0..64) cs[64..128) rvec[128..192) Z@192
__global__ void k_cell(const float* __restrict__ wi, const float* __restrict__ wh,
                       const float* __restrict__ bi, const float* __restrict__ bh,
                       float* __restrict__ st){
  __shared__ float qs[128], hsl[64], g[256];
  int j = threadIdx.x;   // 256
  if (j < 64){ qs[j] = st[j]; hsl[j] = st[j]; }
  else if (j < 128){
    float Z = st[192];
    qs[j] = (Z != 0.0f) ? st[128 + (j-64)]/Z : 0.0f;
  }
  __syncthreads();
  float a = bi[j] + bh[j];
  #pragma unroll 8
  for (int k = 0; k < 128; ++k) a += qs[k]*wi[j*128 + k];
  #pragma unroll 8
  for (int k = 0; k < 64;  ++k) a += hsl[k]*wh[j*64 + k];
  g[j] = a;
  __syncthreads();
  if (j < 64){
    float iv = sigm(g[j]), fv = sigm(g[64+j]);
    float gv = tanhf(g[128+j]), ov = sigm(g[192+j]);
    float c = fv*st[64+j] + iv*gv;
    st[64+j] = c;
    st[j] = ov*tanhf(c);
  } else if (j < 128){
    st[128 + (j-64)] = 0.0f;    // zero rvec accumulator
  } else if (j == 128){
    st[192] = 0.0f;             // zero Z
  }
}

// fused attention: e = out@hs, w = exp(e) (no max needed, |e|<=64), Z += sum w, rvec += w*out
__global__ void k_s2s(const float* __restrict__ out, float* __restrict__ st){
  __shared__ float ob[128*65];
  __shared__ float wl[128], zred[128], hsl[64], part[256];
  int tid = threadIdx.x;      // 256
  int n0 = blockIdx.x * 128;
  if (tid < 64) hsl[tid] = st[tid];
  #pragma unroll
  for (int rr = 0; rr < 8; ++rr){
    int idx = rr*1024 + tid*4;
    int nl = idx >> 6, jj = idx & 63;
    float4 v = make_float4(0.f,0.f,0.f,0.f);
    if (n0 + nl < NN) v = *reinterpret_cast<const float4*>(&out[(size_t)(n0+nl)*64 + jj]);
    ob[nl*65 + jj + 0] = v.x; ob[nl*65 + jj + 1] = v.y;
    ob[nl*65 + jj + 2] = v.z; ob[nl*65 + jj + 3] = v.w;
  }
  __syncthreads();
  if (tid < 128){
    float e = 0.f;
    #pragma unroll 8
    for (int jj = 0; jj < 64; ++jj) e += ob[tid*65 + jj]*hsl[jj];
    float wv = (n0 + tid < NN) ? expf(e) : 0.f;
    wl[tid] = wv; zred[tid] = wv;
  }
  __syncthreads();
  // Z reduction over zred[0..128)
  if (tid < 64) zred[tid] += zred[tid + 64];
  __syncthreads();
  if (tid < 32) zred[tid] += zred[tid + 32];
  __syncthreads();
  if (tid < 16) zred[tid] += zred[tid + 16];
  __syncthreads();
  if (tid < 8) zred[tid] += zred[tid + 8];
  __syncthreads();
  if (tid == 0){
    float z = zred[0]+zred[1]+zred[2]+zred[3]+zred[4]+zred[5]+zred[6]+zred[7];
    atomicAdd(&st[192], z);
  }
  // rvec partials: thread (g = tid>>6, d = tid&63) over 32 nodes
  {
    int gq = tid >> 6, d = tid & 63;
    float acc = 0.f;
    #pragma unroll 8
    for (int i = 0; i < 32; ++i){
      int nl = gq*32 + i;
      acc += wl[nl]*ob[nl*65 + d];
    }
    part[tid] = acc;
  }
  __syncthreads();
  if (tid < 64)
    atomicAdd(&st[128 + tid], part[tid] + part[64+tid] + part[128+tid] + part[192+tid]);
}

// ------------- head -------------
__global__ void k_z(const float* __restrict__ out, const float* __restrict__ st,
                    const int* __restrict__ nonring, float* __restrict__ z){
  int idx = blockIdx.x*256 + threadIdx.x;         // T*384 exact
  int t = idx / 384, c = idx % 384;
  float v;
  if (c < 256){
    int a = c*16 + (t >> 6);
    int node = nonring[a];
    v = out[(size_t)node*64 + (t & 63)];
  } else {
    int pi = t >> 3;                              // pool index (quirky repeat)
    v = (pi < 64) ? st[pi] : st[128 + (pi - 64)] / st[192];
  }
  z[idx] = v;
}

// memory LSTM cell batched 8 rows/block: hm = sig(go)*tanh(sig(gi)*tanh(gg))
__global__ void k_mem(const float* __restrict__ z, const float* __restrict__ wit,
                      const float* __restrict__ bi, const float* __restrict__ bh,
                      float* __restrict__ hm){
  __shared__ float zs[8][384];
  int j = threadIdx.x;             // 384
  int t0 = blockIdx.x * 8;         // grid 128 exact
  #pragma unroll
  for (int r = 0; r < 8; ++r) zs[r][j] = z[(size_t)(t0+r)*384 + j];
  __syncthreads();
  float gi[8], gg[8], go[8];
  #pragma unroll
  for (int r = 0; r < 8; ++r){
    gi[r] = bi[j]      + bh[j];
    gg[r] = bi[768+j]  + bh[768+j];
    go[r] = bi[1152+j] + bh[1152+j];
  }
  for (int k = 0; k < 384; ++k){
    const float* wr = wit + (size_t)k*1536;
    float wiv = wr[j], wgv = wr[768+j], wov = wr[1152+j];
    #pragma unroll
    for (int r = 0; r < 8; ++r){
      float zv = zs[r][k];
      gi[r] += zv*wiv; gg[r] += zv*wgv; go[r] += zv*wov;
    }
  }
  #pragma unroll
  for (int r = 0; r < 8; ++r){
    float cm = sigm(gi[r])*tanhf(gg[r]);
    hm[(size_t)(t0+r)*384 + j] = sigm(go[r])*tanhf(cm);
  }
}

__global__ void k_fin(const float* __restrict__ hm, const float* __restrict__ W1t,
                      const float* __restrict__ b1, const float* __restrict__ W2,
                      const float* __restrict__ b2, float* __restrict__ y){
  __shared__ float hsm[384];
  __shared__ float hid[128];
  int t = blockIdx.x, j = threadIdx.x;            // 128 threads
  hsm[j]     = hm[(size_t)t*384 + j];
  hsm[128+j] = hm[(size_t)t*384 + 128 + j];
  hsm[256+j] = hm[(size_t)t*384 + 256 + j];
  __syncthreads();
  float a = b1[j];
  for (int k = 0; k < 384; ++k) a += hsm[k]*W1t[k*128 + j];
  hid[j] = fmaxf(a, 0.0f);
  __syncthreads();
  if (j < 6){
    float acc = b2[j];
    #pragma unroll 8
    for (int k = 0; k < 128; ++k) acc += hid[k]*W2[j*128 + k];
    y[t*6 + j] = acc;
  }
}

extern "C" void kernel_launch(void* const* d_in, const int* in_sizes, int n_in,
                              void* d_out, int out_size, void* d_ws, size_t ws_size,
                              hipStream_t stream){
  const float* x      = (const float*)d_in[0];
  const float* ea     = (const float*)d_in[1];
  const float* W0     = (const float*)d_in[2];
  const float* b0     = (const float*)d_in[3];
  const float* We1    = (const float*)d_in[4];
  const float* be1    = (const float*)d_in[5];
  const float* We2    = (const float*)d_in[6];
  const float* be2    = (const float*)d_in[7];
  const float* root   = (const float*)d_in[8];
  const float* conv_b = (const float*)d_in[9];
  const float* gwih   = (const float*)d_in[10];
  const float* gwhh   = (const float*)d_in[11];
  const float* gbih   = (const float*)d_in[12];
  const float* gbhh   = (const float*)d_in[13];
  const float* s2swi  = (const float*)d_in[14];
  const float* s2swh  = (const float*)d_in[15];
  const float* s2sbi  = (const float*)d_in[16];
  const float* s2sbh  = (const float*)d_in[17];
  const float* memwi  = (const float*)d_in[18];
  const float* membi  = (const float*)d_in[20];
  const float* membh  = (const float*)d_in[21];
  const float* W1     = (const float*)d_in[22];
  const float* b1     = (const float*)d_in[23];
  const float* W2     = (const float*)d_in[24];
  const float* b2     = (const float*)d_in[25];
  const int*   eidx   = (const int*)d_in[26];
  const int*   nonr   = (const int*)d_in[27];
  const int* src = eidx, *dst = eidx + NE;
  float* y = (float*)d_out;

  char* wsb = (char*)d_ws;
  size_t off = 0;
  auto alloc = [&](size_t bytes){ size_t o = off; off += (bytes + 255) & ~(size_t)255; return o; };
  float* out    = (float*)(wsb + alloc((size_t)NN*64*4));
  float* h      = (float*)(wsb + alloc((size_t)NN*64*4));
  float* agg    = (float*)(wsb + alloc((size_t)NN*64*4));
  float* deg    = (float*)(wsb + alloc((size_t)NN*4));
  float* st     = (float*)(wsb + alloc(256*4));
  float* z      = (float*)(wsb + alloc((size_t)NT*384*4));
  float* hm     = (float*)(wsb + alloc((size_t)NT*384*4));
  float* memwit = (float*)(wsb + alloc((size_t)1536*384*4));
  float* W1t    = (float*)(wsb + alloc((size_t)128*384*4));
  float* gwih_t = (float*)(wsb + alloc((size_t)192*64*4));
  float* gwhh_t = (float*)(wsb + alloc((size_t)192*64*4));
  ushortT* Rbf  = (ushortT*)(wsb + alloc((size_t)NE*128*2));
  ushortT* We2bf= (ushortT*)(wsb + alloc((size_t)4096*128*2));
  (void)ws_size; (void)n_in; (void)in_sizes; (void)out_size;

  hipMemsetAsync(deg, 0, (size_t)NN*4, stream);
  hipMemsetAsync(st, 0, 256*4, stream);
  k_lin0<<<NN*64/256, 256, 0, stream>>>(x, W0, b0, out, h);
  k_deg<<<(NE+255)/256, 256, 0, stream>>>(dst, deg);
  k_invdeg<<<(NN+255)/256, 256, 0, stream>>>(deg);
  k_edgemlp<<<NE*128/256, 256, 0, stream>>>(ea, We1, be1, Rbf);
  k_cvt<<<(4096*128+255)/256, 256, 0, stream>>>(We2, We2bf, 4096*128);
  k_tr<<<(1536*384+255)/256, 256, 0, stream>>>(memwi, memwit, 1536, 384);
  k_tr<<<(128*384+255)/256, 256, 0, stream>>>(W1, W1t, 128, 384);
  k_tr<<<(192*64+255)/256, 256, 0, stream>>>(gwih, gwih_t, 192, 64);
  k_tr<<<(192*64+255)/256, 256, 0, stream>>>(gwhh, gwhh_t, 192, 64);

  for (int it = 0; it < 6; ++it){
    hipMemsetAsync(agg, 0, (size_t)NN*64*4, stream);
    k_fmsg<<<(NE + EB - 1)/EB, 256, 0, stream>>>(Rbf, We2bf, be2, out, src, dst, agg);
    k_gru<<<NN/16, 256, 0, stream>>>(agg, deg, root, conv_b, gwih_t, gwhh_t,
                                     gbih, gbhh, out, h);
  }

  for (int it = 0; it < 6; ++it){
    k_cell<<<1, 256, 0, stream>>>(s2swi, s2swh, s2sbi, s2sbh, st);
    k_s2s<<<(NN + 127)/128, 256, 0, stream>>>(out, st);
  }

  k_z<<<NT*384/256, 256, 0, stream>>>(out, st, nonr, z);
  k_mem<<<128, 384, 0, stream>>>(z, memwit, membi, membh, hm);
  k_fin<<<NT, 128, 0, stream>>>(hm, W1t, b1, W2, b2, y);
}

// Round 3
// 1029.769 us; speedup vs baseline: 1.8312x; 1.8312x over previous
//
#include <hip/hip_runtime.h>
#include <hip/hip_bf16.h>

#define NN 20000
#define NE 60000
#define NT 1024

typedef unsigned short ushortT;
typedef __attribute__((ext_vector_type(8))) short bf16x8;
typedef __attribute__((ext_vector_type(4))) float f32x4;

__device__ __forceinline__ float sigm(float x){ return 1.0f/(1.0f+expf(-x)); }
__device__ __forceinline__ float bfu2f(ushortT u){ return __uint_as_float(((unsigned)u)<<16); }
__device__ __forceinline__ ushortT f2bfu(float f){
  __hip_bfloat16 b = __float2bfloat16(f);
  return *reinterpret_cast<ushortT*>(&b);
}

// ---------------- lin0: out = relu(x @ W0.T + b0); h = out ----------------
__global__ void k_lin0(const float* __restrict__ x, const float* __restrict__ W0,
                       const float* __restrict__ b0, float* __restrict__ out,
                       float* __restrict__ h){
  int idx = blockIdx.x*256 + threadIdx.x;       // N*64 exact
  int n = idx >> 6, j = idx & 63;
  float a = b0[j] + x[n*3+0]*W0[j*3+0] + x[n*3+1]*W0[j*3+1] + x[n*3+2]*W0[j*3+2];
  a = fmaxf(a, 0.0f);
  out[idx] = a; h[idx] = a;
}

__global__ void k_deg(const int* __restrict__ dst, float* __restrict__ deg){
  int e = blockIdx.x*256 + threadIdx.x;
  if (e < NE) atomicAdd(&deg[dst[e]], 1.0f);
}
__global__ void k_invdeg(float* __restrict__ deg){
  int n = blockIdx.x*256 + threadIdx.x;
  if (n < NN) deg[n] = 1.0f/fmaxf(deg[n], 1.0f);
}

// ------------- edge MLP hidden: R = relu(edge_attr @ We1.T + be1) (bf16) ----
__global__ void k_edgemlp(const float* __restrict__ ea, const float* __restrict__ We1,
                          const float* __restrict__ be1, ushortT* __restrict__ Rbf){
  int idx = blockIdx.x*256 + threadIdx.x;       // E*128 exact
  int e = idx >> 7, k = idx & 127;
  float a = be1[k];
  #pragma unroll
  for (int j = 0; j < 7; ++j) a += ea[e*7+j]*We1[k*7+j];
  Rbf[idx] = f2bfu(fmaxf(a, 0.0f));
}

// f32 -> bf16 copy (same layout)
__global__ void k_cvt(const float* __restrict__ in, ushortT* __restrict__ outp, int nelem){
  int idx = blockIdx.x*256 + threadIdx.x;
  if (idx < nelem) outp[idx] = f2bfu(in[idx]);
}

// generic transpose: in [R,C] -> out [C,R]
__global__ void k_tr(const float* __restrict__ in, float* __restrict__ out, int R, int C){
  int idx = blockIdx.x*256 + threadIdx.x;
  if (idx < R*C){ int r = idx / C, c = idx % C; out[c*R + r] = in[idx]; }
}

// ---------- fused NNConv message: agg[dst[e]] += out[src[e]] @ (R[e]@We2^T + be2) ----------
// Grid: (NE/EB) x 4 f-quarters. Block 256 thr (4 waves), EB=256 edges; wave owns 64 edges
// (4 row-tiles of 16). Per d-step (d=0..63): B-tile = We2 rows [d*64+fq*16, +16) x k128
// staged to LDS (double-buffered) via global_load_lds with pre-swizzled source
// (slot ^= row&7) so ds_read_b128 fragment reads are conflict-free.
// msg[e][f] += o[src[e]][d] * (D[e][d*64+fq*16+f] + be2[...]),  f = fq*16 + l15.
#define EB 256
__global__ __launch_bounds__(256) void k_fmsg(
    const ushortT* __restrict__ Rbf, const ushortT* __restrict__ We2bf,
    const float* __restrict__ be2, const float* __restrict__ out,
    const int* __restrict__ src, const int* __restrict__ dst,
    float* __restrict__ agg)
{
  __shared__ float o_sT[64][260];      // out[src[e]] transposed [d][edge], pad 260
  __shared__ ushortT bufB[2][2048];    // 16 rows x 128 k bf16, swizzled slots
  __shared__ float be2_s[1024];        // be2[d*64 + fq*16 + i] at [d*16+i]
  __shared__ int dst_s[EB];

  int tid = threadIdx.x;
  int e0 = blockIdx.x * EB;
  int fq = blockIdx.y;                 // 0..3
  int w = tid >> 6, lane = tid & 63;
  int l15 = lane & 15, g = lane >> 4;  // g in 0..3

  // ---- prologue: dst + o gather (transposed), be2 stage, B tile 0 stage ----
  {
    int ge = e0 + tid;
    int sn = (ge < NE) ? src[ge] : -1;
    dst_s[tid] = (ge < NE) ? dst[ge] : -1;
    const float* op = out + (size_t)((sn < 0) ? 0 : sn)*64;
    #pragma unroll
    for (int i = 0; i < 16; ++i){
      float4 v = make_float4(0.f,0.f,0.f,0.f);
      if (sn >= 0) v = *reinterpret_cast<const float4*>(op + i*4);
      o_sT[i*4+0][tid] = v.x;
      o_sT[i*4+1][tid] = v.y;
      o_sT[i*4+2][tid] = v.z;
      o_sT[i*4+3][tid] = v.w;
    }
  }
  {
    int i = tid*4;
    float4 v = *reinterpret_cast<const float4*>(&be2[(i>>4)*64 + fq*16 + (i&15)]);
    *reinterpret_cast<float4*>(&be2_s[i]) = v;
  }
  {
    int grow = (w<<2) + g;                    // 0..15
    int gslot = l15 ^ (grow & 7);
    const ushortT* gp = We2bf + (size_t)(fq*16 + grow)*128 + gslot*8;
    __builtin_amdgcn_global_load_lds(
        (const __attribute__((address_space(1))) void*)gp,
        (__attribute__((address_space(3))) void*)&bufB[0][w*512], 16, 0, 0);
  }

  // A fragments: R rows for this wave's 64 edges, all K=128 (4 k-steps)
  bf16x8 af[4][4];
  #pragma unroll
  for (int t = 0; t < 4; ++t){
    #pragma unroll
    for (int ks = 0; ks < 4; ++ks){
      int ge = e0 + w*64 + t*16 + l15;
      bf16x8 z = {0,0,0,0,0,0,0,0};
      af[t][ks] = (ge < NE) ? *reinterpret_cast<const bf16x8*>(Rbf + (size_t)ge*128 + ks*32 + g*8) : z;
    }
  }

  float msg[4][4] = {{0.f,0.f,0.f,0.f},{0.f,0.f,0.f,0.f},{0.f,0.f,0.f,0.f},{0.f,0.f,0.f,0.f}};
  __syncthreads();   // tile 0 staged (barrier drains vmcnt), o_sT/be2_s ready

  for (int d = 0; d < 64; ++d){
    int cur = d & 1;
    if (d < 63){
      int grow = (w<<2) + g;
      int gslot = l15 ^ (grow & 7);
      const ushortT* gp = We2bf + (size_t)((d+1)*64 + fq*16 + grow)*128 + gslot*8;
      __builtin_amdgcn_global_load_lds(
          (const __attribute__((address_space(1))) void*)gp,
          (__attribute__((address_space(3))) void*)&bufB[cur^1][w*512], 16, 0, 0);
    }
    // B fragments from swizzled LDS: row l15, slot (ks*4+g) ^ (l15&7)
    bf16x8 bf[4];
    #pragma unroll
    for (int ks = 0; ks < 4; ++ks)
      bf[ks] = *reinterpret_cast<const bf16x8*>(&bufB[cur][ l15*128 + (((ks*4+g) ^ (l15&7))<<3) ]);

    f32x4 ac[4];
    #pragma unroll
    for (int t = 0; t < 4; ++t){ ac[t][0]=0.f; ac[t][1]=0.f; ac[t][2]=0.f; ac[t][3]=0.f; }
    #pragma unroll
    for (int ks = 0; ks < 4; ++ks){
      #pragma unroll
      for (int t = 0; t < 4; ++t)
        ac[t] = __builtin_amdgcn_mfma_f32_16x16x32_bf16(af[t][ks], bf[ks], ac[t], 0, 0, 0);
    }
    float be2v = be2_s[d*16 + l15];
    #pragma unroll
    for (int t = 0; t < 4; ++t){
      float4 ov = *reinterpret_cast<const float4*>(&o_sT[d][w*64 + t*16 + g*4]);
      msg[t][0] += ov.x * (ac[t][0] + be2v);
      msg[t][1] += ov.y * (ac[t][1] + be2v);
      msg[t][2] += ov.z * (ac[t][2] + be2v);
      msg[t][3] += ov.w * (ac[t][3] + be2v);
    }
    __syncthreads();   // tile d+1 ready; all reads of bufB[cur] done
  }

  #pragma unroll
  for (int t = 0; t < 4; ++t){
    #pragma unroll
    for (int r = 0; r < 4; ++r){
      int el = w*64 + t*16 + g*4 + r;
      int tn = dst_s[el];
      if (tn >= 0) atomicAdd(&agg[(size_t)tn*64 + fq*16 + l15], msg[t][r]);
    }
  }
}

// ------------- NNConv epilogue + GRU cell (16 nodes / block, 4 per thread) ----------------
__global__ void k_gru(const float* __restrict__ agg, const float* __restrict__ inv_deg,
                      const float* __restrict__ root, const float* __restrict__ conv_b,
                      const float* __restrict__ wih_t, const float* __restrict__ whh_t,
                      const float* __restrict__ bih, const float* __restrict__ bhh,
                      float* __restrict__ out, float* __restrict__ h){
  __shared__ float os[16][64], hsm[16][64], ms[16][64];
  int tid = threadIdx.x;
  int j = tid & 63, sub = tid >> 6;   // sub 0..3
  int n0 = blockIdx.x * 16;
  #pragma unroll
  for (int i = 0; i < 4; ++i){
    int nl = sub + 4*i;
    os[nl][j]  = out[(size_t)(n0+nl)*64 + j];
    hsm[nl][j] = h[(size_t)(n0+nl)*64 + j];
  }
  __syncthreads();
  float a[4];
  #pragma unroll
  for (int i = 0; i < 4; ++i){
    int nl = sub + 4*i;
    a[i] = agg[(size_t)(n0+nl)*64 + j]*inv_deg[n0+nl] + conv_b[j];
  }
  for (int d = 0; d < 64; ++d){
    float rdj = root[d*64 + j];
    #pragma unroll
    for (int i = 0; i < 4; ++i) a[i] += os[sub + 4*i][d]*rdj;
  }
  #pragma unroll
  for (int i = 0; i < 4; ++i) ms[sub + 4*i][j] = fmaxf(a[i], 0.0f);
  __syncthreads();
  float gxr[4], gxz[4], gxn[4], ghr[4], ghz[4], ghn[4];
  #pragma unroll
  for (int i = 0; i < 4; ++i){
    gxr[i] = bih[j];     gxz[i] = bih[64+j];  gxn[i] = bih[128+j];
    ghr[i] = bhh[j];     ghz[i] = bhh[64+j];  ghn[i] = bhh[128+j];
  }
  for (int d = 0; d < 64; ++d){
    float wir = wih_t[d*192 + j], wiz = wih_t[d*192 + 64 + j], win = wih_t[d*192 + 128 + j];
    float whr = whh_t[d*192 + j], whz = whh_t[d*192 + 64 + j], whn = whh_t[d*192 + 128 + j];
    #pragma unroll
    for (int i = 0; i < 4; ++i){
      float mv = ms[sub + 4*i][d], hv = hsm[sub + 4*i][d];
      gxr[i] += mv*wir; gxz[i] += mv*wiz; gxn[i] += mv*win;
      ghr[i] += hv*whr; ghz[i] += hv*whz; ghn[i] += hv*whn;
    }
  }
  #pragma unroll
  for (int i = 0; i < 4; ++i){
    int nl = sub + 4*i;
    float r = sigm(gxr[i]+ghr[i]), zg = sigm(gxz[i]+ghz[i]);
    float nn_ = tanhf(gxn[i] + r*ghn[i]);
    float hn = (1.0f - zg)*nn_ + zg*hsm[nl][j];
    h[(size_t)(n0+nl)*64 + j]   = hn;
    out[(size_t)(n0+nl)*64 + j] = hn;
  }
}

// ------------- Set2Set -------------
// st layout (floats): hs[0..64) cs[64..128) rvec[128..192) Z@192
__global__ void k_cell(const float* __restrict__ wi, const float* __restrict__ wh,
                       const float* __restrict__ bi, const float* __restrict__ bh,
                       float* __restrict__ st){
  __shared__ float qs[128], hsl[64], g[256];
  int j = threadIdx.x;   // 256
  if (j < 64){ qs[j] = st[j]; hsl[j] = st[j]; }
  else if (j < 128){
    float Z = st[192];
    qs[j] = (Z != 0.0f) ? st[128 + (j-64)]/Z : 0.0f;
  }
  __syncthreads();
  float a = bi[j] + bh[j];
  #pragma unroll 8
  for (int k = 0; k < 128; ++k) a += qs[k]*wi[j*128 + k];
  #pragma unroll 8
  for (int k = 0; k < 64;  ++k) a += hsl[k]*wh[j*64 + k];
  g[j] = a;
  __syncthreads();
  if (j < 64){
    float iv = sigm(g[j]), fv = sigm(g[64+j]);
    float gv = tanhf(g[128+j]), ov = sigm(g[192+j]);
    float c = fv*st[64+j] + iv*gv;
    st[64+j] = c;
    st[j] = ov*tanhf(c);
  } else if (j < 128){
    st[128 + (j-64)] = 0.0f;    // zero rvec accumulator
  } else if (j == 128){
    st[192] = 0.0f;             // zero Z
  }
}

// fused attention: e = out@hs, w = exp(e) (no max needed, |e|<=64), Z += sum w, rvec += w*out
__global__ void k_s2s(const float* __restrict__ out, float* __restrict__ st){
  __shared__ float ob[128*65];
  __shared__ float wl[128], zred[128], hsl[64], part[256];
  int tid = threadIdx.x;      // 256
  int n0 = blockIdx.x * 128;
  if (tid < 64) hsl[tid] = st[tid];
  #pragma unroll
  for (int rr = 0; rr < 8; ++rr){
    int idx = rr*1024 + tid*4;
    int nl = idx >> 6, jj = idx & 63;
    float4 v = make_float4(0.f,0.f,0.f,0.f);
    if (n0 + nl < NN) v = *reinterpret_cast<const float4*>(&out[(size_t)(n0+nl)*64 + jj]);
    ob[nl*65 + jj + 0] = v.x; ob[nl*65 + jj + 1] = v.y;
    ob[nl*65 + jj + 2] = v.z; ob[nl*65 + jj + 3] = v.w;
  }
  __syncthreads();
  if (tid < 128){
    float e = 0.f;
    #pragma unroll 8
    for (int jj = 0; jj < 64; ++jj) e += ob[tid*65 + jj]*hsl[jj];
    float wv = (n0 + tid < NN) ? expf(e) : 0.f;
    wl[tid] = wv; zred[tid] = wv;
  }
  __syncthreads();
  // Z reduction over zred[0..128)
  if (tid < 64) zred[tid] += zred[tid + 64];
  __syncthreads();
  if (tid < 32) zred[tid] += zred[tid + 32];
  __syncthreads();
  if (tid < 16) zred[tid] += zred[tid + 16];
  __syncthreads();
  if (tid < 8) zred[tid] += zred[tid + 8];
  __syncthreads();
  if (tid == 0){
    float z = zred[0]+zred[1]+zred[2]+zred[3]+zred[4]+zred[5]+zred[6]+zred[7];
    atomicAdd(&st[192], z);
  }
  // rvec partials: thread (g = tid>>6, d = tid&63) over 32 nodes
  {
    int gq = tid >> 6, d = tid & 63;
    float acc = 0.f;
    #pragma unroll 8
    for (int i = 0; i < 32; ++i){
      int nl = gq*32 + i;
      acc += wl[nl]*ob[nl*65 + d];
    }
    part[tid] = acc;
  }
  __syncthreads();
  if (tid < 64)
    atomicAdd(&st[128 + tid], part[tid] + part[64+tid] + part[128+tid] + part[192+tid]);
}

// ------------- head -------------
__global__ void k_z(const float* __restrict__ out, const float* __restrict__ st,
                    const int* __restrict__ nonring, float* __restrict__ z){
  int idx = blockIdx.x*256 + threadIdx.x;         // T*384 exact
  int t = idx / 384, c = idx % 384;
  float v;
  if (c < 256){
    int a = c*16 + (t >> 6);
    int node = nonring[a];
    v = out[(size_t)node*64 + (t & 63)];
  } else {
    int pi = t >> 3;                              // pool index (quirky repeat)
    v = (pi < 64) ? st[pi] : st[128 + (pi - 64)] / st[192];
  }
  z[idx] = v;
}

// memory LSTM cell batched 8 rows/block: hm = sig(go)*tanh(sig(gi)*tanh(gg))
__global__ void k_mem(const float* __restrict__ z, const float* __restrict__ wit,
                      const float* __restrict__ bi, const float* __restrict__ bh,
                      float* __restrict__ hm){
  __shared__ float zs[8][384];
  int j = threadIdx.x;             // 384
  int t0 = blockIdx.x * 8;         // grid 128 exact
  #pragma unroll
  for (int r = 0; r < 8; ++r) zs[r][j] = z[(size_t)(t0+r)*384 + j];
  __syncthreads();
  float gi[8], gg[8], go[8];
  #pragma unroll
  for (int r = 0; r < 8; ++r){
    gi[r] = bi[j]      + bh[j];
    gg[r] = bi[768+j]  + bh[768+j];
    go[r] = bi[1152+j] + bh[1152+j];
  }
  for (int k = 0; k < 384; ++k){
    const float* wr = wit + (size_t)k*1536;
    float wiv = wr[j], wgv = wr[768+j], wov = wr[1152+j];
    #pragma unroll
    for (int r = 0; r < 8; ++r){
      float zv = zs[r][k];
      gi[r] += zv*wiv; gg[r] += zv*wgv; go[r] += zv*wov;
    }
  }
  #pragma unroll
  for (int r = 0; r < 8; ++r){
    float cm = sigm(gi[r])*tanhf(gg[r]);
    hm[(size_t)(t0+r)*384 + j] = sigm(go[r])*tanhf(cm);
  }
}

__global__ void k_fin(const float* __restrict__ hm, const float* __restrict__ W1t,
                      const float* __restrict__ b1, const float* __restrict__ W2,
                      const float* __restrict__ b2, float* __restrict__ y){
  __shared__ float hsm[384];
  __shared__ float hid[128];
  int t = blockIdx.x, j = threadIdx.x;            // 128 threads
  hsm[j]     = hm[(size_t)t*384 + j];
  hsm[128+j] = hm[(size_t)t*384 + 128 + j];
  hsm[256+j] = hm[(size_t)t*384 + 256 + j];
  __syncthreads();
  float a = b1[j];
  for (int k = 0; k < 384; ++k) a += hsm[k]*W1t[k*128 + j];
  hid[j] = fmaxf(a, 0.0f);
  __syncthreads();
  if (j < 6){
    float acc = b2[j];
    #pragma unroll 8
    for (int k = 0; k < 128; ++k) acc += hid[k]*W2[j*128 + k];
    y[t*6 + j] = acc;
  }
}

extern "C" void kernel_launch(void* const* d_in, const int* in_sizes, int n_in,
                              void* d_out, int out_size, void* d_ws, size_t ws_size,
                              hipStream_t stream){
  const float* x      = (const float*)d_in[0];
  const float* ea     = (const float*)d_in[1];
  const float* W0     = (const float*)d_in[2];
  const float* b0     = (const float*)d_in[3];
  const float* We1    = (const float*)d_in[4];
  const float* be1    = (const float*)d_in[5];
  const float* We2    = (const float*)d_in[6];
  const float* be2    = (const float*)d_in[7];
  const float* root   = (const float*)d_in[8];
  const float* conv_b = (const float*)d_in[9];
  const float* gwih   = (const float*)d_in[10];
  const float* gwhh   = (const float*)d_in[11];
  const float* gbih   = (const float*)d_in[12];
  const float* gbhh   = (const float*)d_in[13];
  const float* s2swi  = (const float*)d_in[14];
  const float* s2swh  = (const float*)d_in[15];
  const float* s2sbi  = (const float*)d_in[16];
  const float* s2sbh  = (const float*)d_in[17];
  const float* memwi  = (const float*)d_in[18];
  const float* membi  = (const float*)d_in[20];
  const float* membh  = (const float*)d_in[21];
  const float* W1     = (const float*)d_in[22];
  const float* b1     = (const float*)d_in[23];
  const float* W2     = (const float*)d_in[24];
  const float* b2     = (const float*)d_in[25];
  const int*   eidx   = (const int*)d_in[26];
  const int*   nonr   = (const int*)d_in[27];
  const int* src = eidx, *dst = eidx + NE;
  float* y = (float*)d_out;

  char* wsb = (char*)d_ws;
  size_t off = 0;
  auto alloc = [&](size_t bytes){ size_t o = off; off += (bytes + 255) & ~(size_t)255; return o; };
  float* out    = (float*)(wsb + alloc((size_t)NN*64*4));
  float* h      = (float*)(wsb + alloc((size_t)NN*64*4));
  float* agg    = (float*)(wsb + alloc((size_t)NN*64*4));
  float* deg    = (float*)(wsb + alloc((size_t)NN*4));
  float* st     = (float*)(wsb + alloc(256*4));
  float* z      = (float*)(wsb + alloc((size_t)NT*384*4));
  float* hm     = (float*)(wsb + alloc((size_t)NT*384*4));
  float* memwit = (float*)(wsb + alloc((size_t)1536*384*4));
  float* W1t    = (float*)(wsb + alloc((size_t)128*384*4));
  float* gwih_t = (float*)(wsb + alloc((size_t)192*64*4));
  float* gwhh_t = (float*)(wsb + alloc((size_t)192*64*4));
  ushortT* Rbf  = (ushortT*)(wsb + alloc((size_t)NE*128*2));
  ushortT* We2bf= (ushortT*)(wsb + alloc((size_t)4096*128*2));
  (void)ws_size; (void)n_in; (void)in_sizes; (void)out_size;

  hipMemsetAsync(deg, 0, (size_t)NN*4, stream);
  hipMemsetAsync(st, 0, 256*4, stream);
  k_lin0<<<NN*64/256, 256, 0, stream>>>(x, W0, b0, out, h);
  k_deg<<<(NE+255)/256, 256, 0, stream>>>(dst, deg);
  k_invdeg<<<(NN+255)/256, 256, 0, stream>>>(deg);
  k_edgemlp<<<NE*128/256, 256, 0, stream>>>(ea, We1, be1, Rbf);
  k_cvt<<<(4096*128+255)/256, 256, 0, stream>>>(We2, We2bf, 4096*128);
  k_tr<<<(1536*384+255)/256, 256, 0, stream>>>(memwi, memwit, 1536, 384);
  k_tr<<<(128*384+255)/256, 256, 0, stream>>>(W1, W1t, 128, 384);
  k_tr<<<(192*64+255)/256, 256, 0, stream>>>(gwih, gwih_t, 192, 64);
  k_tr<<<(192*64+255)/256, 256, 0, stream>>>(gwhh, gwhh_t, 192, 64);

  for (int it = 0; it < 6; ++it){
    hipMemsetAsync(agg, 0, (size_t)NN*64*4, stream);
    k_fmsg<<<dim3((NE + EB - 1)/EB, 4), 256, 0, stream>>>(Rbf, We2bf, be2, out, src, dst, agg);
    k_gru<<<NN/16, 256, 0, stream>>>(agg, deg, root, conv_b, gwih_t, gwhh_t,
                                     gbih, gbhh, out, h);
  }

  for (int it = 0; it < 6; ++it){
    k_cell<<<1, 256, 0, stream>>>(s2swi, s2swh, s2sbi, s2sbh, st);
    k_s2s<<<(NN + 127)/128, 256, 0, stream>>>(out, st);
  }

  k_z<<<NT*384/256, 256, 0, stream>>>(out, st, nonr, z);
  k_mem<<<128, 384, 0, stream>>>(z, memwit, membi, membh, hm);
  k_fin<<<NT, 128, 0, stream>>>(hm, W1t, b1, W2, b2, y);
}

// Round 4
// 959.457 us; speedup vs baseline: 1.9654x; 1.0733x over previous
//
#include <hip/hip_runtime.h>
#include <hip/hip_bf16.h>

#define NN 20000
#define NE 60000
#define NT 1024

typedef unsigned short ushortT;
typedef __attribute__((ext_vector_type(8))) short bf16x8;
typedef __attribute__((ext_vector_type(4))) float f32x4;

__device__ __forceinline__ float sigm(float x){ return 1.0f/(1.0f+expf(-x)); }
__device__ __forceinline__ float bfu2f(ushortT u){ return __uint_as_float(((unsigned)u)<<16); }
__device__ __forceinline__ ushortT f2bfu(float f){
  __hip_bfloat16 b = __float2bfloat16(f);
  return *reinterpret_cast<ushortT*>(&b);
}

// ---------------- lin0: out = relu(x @ W0.T + b0); h = out ----------------
__global__ void k_lin0(const float* __restrict__ x, const float* __restrict__ W0,
                       const float* __restrict__ b0, float* __restrict__ out,
                       float* __restrict__ h){
  int idx = blockIdx.x*256 + threadIdx.x;       // N*64 exact
  int n = idx >> 6, j = idx & 63;
  float a = b0[j] + x[n*3+0]*W0[j*3+0] + x[n*3+1]*W0[j*3+1] + x[n*3+2]*W0[j*3+2];
  a = fmaxf(a, 0.0f);
  out[idx] = a; h[idx] = a;
}

__global__ void k_deg(const int* __restrict__ dst, float* __restrict__ deg){
  int e = blockIdx.x*256 + threadIdx.x;
  if (e < NE) atomicAdd(&deg[dst[e]], 1.0f);
}
__global__ void k_invdeg(float* __restrict__ deg){
  int n = blockIdx.x*256 + threadIdx.x;
  if (n < NN) deg[n] = 1.0f/fmaxf(deg[n], 1.0f);
}

// ------------- edge MLP hidden: R = relu(edge_attr @ We1.T + be1) (bf16) ----
__global__ void k_edgemlp(const float* __restrict__ ea, const float* __restrict__ We1,
                          const float* __restrict__ be1, ushortT* __restrict__ Rbf){
  int idx = blockIdx.x*256 + threadIdx.x;       // E*128 exact
  int e = idx >> 7, k = idx & 127;
  float a = be1[k];
  #pragma unroll
  for (int j = 0; j < 7; ++j) a += ea[e*7+j]*We1[k*7+j];
  Rbf[idx] = f2bfu(fmaxf(a, 0.0f));
}

// f32 -> bf16 copy (same layout)
__global__ void k_cvt(const float* __restrict__ in, ushortT* __restrict__ outp, int nelem){
  int idx = blockIdx.x*256 + threadIdx.x;
  if (idx < nelem) outp[idx] = f2bfu(in[idx]);
}

// generic transpose: in [R,C] -> out [C,R]
__global__ void k_tr(const float* __restrict__ in, float* __restrict__ out, int R, int C){
  int idx = blockIdx.x*256 + threadIdx.x;
  if (idx < R*C){ int r = idx / C, c = idx % C; out[c*R + r] = in[idx]; }
}

// ---------- fused NNConv message: agg[dst[e]] += out[src[e]] @ (R[e]@We2^T + be2) ----------
// Grid: (NE/EB) x 2 f-halves. Block 256 thr (4 waves), EB=256 edges; wave owns 64 edges
// (4 row-tiles of 16). Per d-step: B-tile = We2 rows [d*64+fh*32, +32) x k128 (8KB bf16)
// staged to LDS (double-buffered) via global_load_lds with pre-swizzled source
// (kslot ^= row&7) so ds_read_b128 fragment reads are conflict-free.
// o[src] cached in LDS as bf16 transposed [d][edge]. LDS total ~50.8KB -> 3 blocks/CU.
#define EB 256
__global__ __launch_bounds__(256, 3) void k_fmsg(
    const ushortT* __restrict__ Rbf, const ushortT* __restrict__ We2bf,
    const float* __restrict__ be2, const float* __restrict__ out,
    const int* __restrict__ src, const int* __restrict__ dst,
    float* __restrict__ agg)
{
  __shared__ ushortT o_sT[64][EB+8];   // bf16 out[src[e]] transposed [d][edge]
  __shared__ ushortT bufB[2][4096];    // 32 rows x 128 k bf16 (8KB each), swizzled slots
  __shared__ int dst_s[EB];

  int tid = threadIdx.x;
  int e0 = blockIdx.x * EB;
  int fh = blockIdx.y;                 // 0..1
  int w = tid >> 6, lane = tid & 63;
  int l15 = lane & 15, g = lane >> 4;  // g in 0..3

  // ---- prologue: dst + o gather (bf16, transposed) ----
  {
    int ge = e0 + tid;
    int sn = (ge < NE) ? src[ge] : -1;
    dst_s[tid] = (ge < NE) ? dst[ge] : -1;
    const float* op = out + (size_t)((sn < 0) ? 0 : sn)*64;
    #pragma unroll
    for (int i = 0; i < 16; ++i){
      float4 v = make_float4(0.f,0.f,0.f,0.f);
      if (sn >= 0) v = *reinterpret_cast<const float4*>(op + i*4);
      o_sT[i*4+0][tid] = f2bfu(v.x);
      o_sT[i*4+1][tid] = f2bfu(v.y);
      o_sT[i*4+2][tid] = f2bfu(v.z);
      o_sT[i*4+3][tid] = f2bfu(v.w);
    }
  }
  // stage B tile for d=0 (2 global_load_lds per wave; linear LDS, pre-swizzled source)
  #pragma unroll
  for (int i = 0; i < 2; ++i){
    int s = (w*2 + i)*64 + lane;          // 0..511
    int row = s >> 4, kslot = s & 15;
    const ushortT* gp = We2bf + (size_t)(fh*32 + row)*128 + ((kslot ^ (row & 7))<<3);
    __builtin_amdgcn_global_load_lds(
        (const __attribute__((address_space(1))) void*)gp,
        (__attribute__((address_space(3))) void*)&bufB[0][(size_t)s*8], 16, 0, 0);
  }

  // A fragments: R rows for this wave's 64 edges, all K=128 (4 k-steps)
  bf16x8 af[4][4];
  #pragma unroll
  for (int t = 0; t < 4; ++t){
    #pragma unroll
    for (int ks = 0; ks < 4; ++ks){
      int ge = e0 + w*64 + t*16 + l15;
      bf16x8 z = {0,0,0,0,0,0,0,0};
      af[t][ks] = (ge < NE) ? *reinterpret_cast<const bf16x8*>(Rbf + (size_t)ge*128 + ks*32 + g*8) : z;
    }
  }

  f32x4 msg[4][2];
  #pragma unroll
  for (int t = 0; t < 4; ++t){
    #pragma unroll
    for (int q = 0; q < 2; ++q){ msg[t][q][0]=0.f; msg[t][q][1]=0.f; msg[t][q][2]=0.f; msg[t][q][3]=0.f; }
  }
  __syncthreads();   // tile 0 staged (barrier drains vmcnt), o_sT ready

  for (int d = 0; d < 64; ++d){
    int cur = d & 1;
    if (d < 63){
      #pragma unroll
      for (int i = 0; i < 2; ++i){
        int s = (w*2 + i)*64 + lane;
        int row = s >> 4, kslot = s & 15;
        const ushortT* gp = We2bf + (size_t)((d+1)*64 + fh*32 + row)*128 + ((kslot ^ (row & 7))<<3);
        __builtin_amdgcn_global_load_lds(
            (const __attribute__((address_space(1))) void*)gp,
            (__attribute__((address_space(3))) void*)&bufB[cur^1][(size_t)s*8], 16, 0, 0);
      }
    }
    // MFMA: ks-inner B loads to bound register liveness
    f32x4 ac[4][2];
    #pragma unroll
    for (int t = 0; t < 4; ++t){
      #pragma unroll
      for (int q = 0; q < 2; ++q){ ac[t][q][0]=0.f; ac[t][q][1]=0.f; ac[t][q][2]=0.f; ac[t][q][3]=0.f; }
    }
    #pragma unroll
    for (int ks = 0; ks < 4; ++ks){
      bf16x8 b0 = *reinterpret_cast<const bf16x8*>(&bufB[cur][ (l15)*128      + ((((ks<<2)+g) ^ (l15&7))<<3) ]);
      bf16x8 b1 = *reinterpret_cast<const bf16x8*>(&bufB[cur][ (16+l15)*128   + ((((ks<<2)+g) ^ (l15&7))<<3) ]);
      #pragma unroll
      for (int t = 0; t < 4; ++t){
        ac[t][0] = __builtin_amdgcn_mfma_f32_16x16x32_bf16(af[t][ks], b0, ac[t][0], 0, 0, 0);
        ac[t][1] = __builtin_amdgcn_mfma_f32_16x16x32_bf16(af[t][ks], b1, ac[t][1], 0, 0, 0);
      }
    }
    float be2v0 = be2[d*64 + fh*32 + l15];
    float be2v1 = be2[d*64 + fh*32 + 16 + l15];
    #pragma unroll
    for (int t = 0; t < 4; ++t){
      ushort4 ou = *reinterpret_cast<const ushort4*>(&o_sT[d][w*64 + t*16 + g*4]);
      float o0 = bfu2f(ou.x), o1 = bfu2f(ou.y), o2 = bfu2f(ou.z), o3 = bfu2f(ou.w);
      msg[t][0][0] += o0*(ac[t][0][0] + be2v0);
      msg[t][0][1] += o1*(ac[t][0][1] + be2v0);
      msg[t][0][2] += o2*(ac[t][0][2] + be2v0);
      msg[t][0][3] += o3*(ac[t][0][3] + be2v0);
      msg[t][1][0] += o0*(ac[t][1][0] + be2v1);
      msg[t][1][1] += o1*(ac[t][1][1] + be2v1);
      msg[t][1][2] += o2*(ac[t][1][2] + be2v1);
      msg[t][1][3] += o3*(ac[t][1][3] + be2v1);
    }
    __syncthreads();   // tile d+1 ready; all reads of bufB[cur] done
  }

  #pragma unroll
  for (int t = 0; t < 4; ++t){
    #pragma unroll
    for (int r = 0; r < 4; ++r){
      int el = w*64 + t*16 + g*4 + r;
      int tn = dst_s[el];
      if (tn >= 0){
        atomicAdd(&agg[(size_t)tn*64 + fh*32 + l15],      msg[t][0][r]);
        atomicAdd(&agg[(size_t)tn*64 + fh*32 + 16 + l15], msg[t][1][r]);
      }
    }
  }
}

// ------------- NNConv epilogue + GRU cell (16 nodes / block, 4 per thread) ----------------
__global__ void k_gru(const float* __restrict__ agg, const float* __restrict__ inv_deg,
                      const float* __restrict__ root, const float* __restrict__ conv_b,
                      const float* __restrict__ wih_t, const float* __restrict__ whh_t,
                      const float* __restrict__ bih, const float* __restrict__ bhh,
                      float* __restrict__ out, float* __restrict__ h){
  __shared__ float os[16][64], hsm[16][64], ms[16][64];
  int tid = threadIdx.x;
  int j = tid & 63, sub = tid >> 6;   // sub 0..3
  int n0 = blockIdx.x * 16;
  #pragma unroll
  for (int i = 0; i < 4; ++i){
    int nl = sub + 4*i;
    os[nl][j]  = out[(size_t)(n0+nl)*64 + j];
    hsm[nl][j] = h[(size_t)(n0+nl)*64 + j];
  }
  __syncthreads();
  float a[4];
  #pragma unroll
  for (int i = 0; i < 4; ++i){
    int nl = sub + 4*i;
    a[i] = agg[(size_t)(n0+nl)*64 + j]*inv_deg[n0+nl] + conv_b[j];
  }
  for (int d = 0; d < 64; ++d){
    float rdj = root[d*64 + j];
    #pragma unroll
    for (int i = 0; i < 4; ++i) a[i] += os[sub + 4*i][d]*rdj;
  }
  #pragma unroll
  for (int i = 0; i < 4; ++i) ms[sub + 4*i][j] = fmaxf(a[i], 0.0f);
  __syncthreads();
  float gxr[4], gxz[4], gxn[4], ghr[4], ghz[4], ghn[4];
  #pragma unroll
  for (int i = 0; i < 4; ++i){
    gxr[i] = bih[j];     gxz[i] = bih[64+j];  gxn[i] = bih[128+j];
    ghr[i] = bhh[j];     ghz[i] = bhh[64+j];  ghn[i] = bhh[128+j];
  }
  for (int d = 0; d < 64; ++d){
    float wir = wih_t[d*192 + j], wiz = wih_t[d*192 + 64 + j], win = wih_t[d*192 + 128 + j];
    float whr = whh_t[d*192 + j], whz = whh_t[d*192 + 64 + j], whn = whh_t[d*192 + 128 + j];
    #pragma unroll
    for (int i = 0; i < 4; ++i){
      float mv = ms[sub + 4*i][d], hv = hsm[sub + 4*i][d];
      gxr[i] += mv*wir; gxz[i] += mv*wiz; gxn[i] += mv*win;
      ghr[i] += hv*whr; ghz[i] += hv*whz; ghn[i] += hv*whn;
    }
  }
  #pragma unroll
  for (int i = 0; i < 4; ++i){
    int nl = sub + 4*i;
    float r = sigm(gxr[i]+ghr[i]), zg = sigm(gxz[i]+ghz[i]);
    float nn_ = tanhf(gxn[i] + r*ghn[i]);
    float hn = (1.0f - zg)*nn_ + zg*hsm[nl][j];
    h[(size_t)(n0+nl)*64 + j]   = hn;
    out[(size_t)(n0+nl)*64 + j] = hn;
  }
}

// ------------- Set2Set -------------
// st layout (floats): hs[0..64) cs[64..128) rvec[128..192) Z@192
__global__ void k_cell(const float* __restrict__ wi, const float* __restrict__ wh,
                       const float* __restrict__ bi, const float* __restrict__ bh,
                       float* __restrict__ st){
  __shared__ float qs[128], hsl[64], g[256];
  int j = threadIdx.x;   // 256
  if (j < 64){ qs[j] = st[j]; hsl[j] = st[j]; }
  else if (j < 128){
    float Z = st[192];
    qs[j] = (Z != 0.0f) ? st[128 + (j-64)]/Z : 0.0f;
  }
  __syncthreads();
  float a = bi[j] + bh[j];
  #pragma unroll 8
  for (int k = 0; k < 128; ++k) a += qs[k]*wi[j*128 + k];
  #pragma unroll 8
  for (int k = 0; k < 64;  ++k) a += hsl[k]*wh[j*64 + k];
  g[j] = a;
  __syncthreads();
  if (j < 64){
    float iv = sigm(g[j]), fv = sigm(g[64+j]);
    float gv = tanhf(g[128+j]), ov = sigm(g[192+j]);
    float c = fv*st[64+j] + iv*gv;
    st[64+j] = c;
    st[j] = ov*tanhf(c);
  } else if (j < 128){
    st[128 + (j-64)] = 0.0f;    // zero rvec accumulator
  } else if (j == 128){
    st[192] = 0.0f;             // zero Z
  }
}

// fused attention: e = out@hs, w = exp(e) (no max needed, |e|<=64), Z += sum w, rvec += w*out
__global__ void k_s2s(const float* __restrict__ out, float* __restrict__ st){
  __shared__ float ob[128*65];
  __shared__ float wl[128], zred[128], hsl[64], part[256];
  int tid = threadIdx.x;      // 256
  int n0 = blockIdx.x * 128;
  if (tid < 64) hsl[tid] = st[tid];
  #pragma unroll
  for (int rr = 0; rr < 8; ++rr){
    int idx = rr*1024 + tid*4;
    int nl = idx >> 6, jj = idx & 63;
    float4 v = make_float4(0.f,0.f,0.f,0.f);
    if (n0 + nl < NN) v = *reinterpret_cast<const float4*>(&out[(size_t)(n0+nl)*64 + jj]);
    ob[nl*65 + jj + 0] = v.x; ob[nl*65 + jj + 1] = v.y;
    ob[nl*65 + jj + 2] = v.z; ob[nl*65 + jj + 3] = v.w;
  }
  __syncthreads();
  if (tid < 128){
    float e = 0.f;
    #pragma unroll 8
    for (int jj = 0; jj < 64; ++jj) e += ob[tid*65 + jj]*hsl[jj];
    float wv = (n0 + tid < NN) ? expf(e) : 0.f;
    wl[tid] = wv; zred[tid] = wv;
  }
  __syncthreads();
  // Z reduction over zred[0..128)
  if (tid < 64) zred[tid] += zred[tid + 64];
  __syncthreads();
  if (tid < 32) zred[tid] += zred[tid + 32];
  __syncthreads();
  if (tid < 16) zred[tid] += zred[tid + 16];
  __syncthreads();
  if (tid < 8) zred[tid] += zred[tid + 8];
  __syncthreads();
  if (tid == 0){
    float z = zred[0]+zred[1]+zred[2]+zred[3]+zred[4]+zred[5]+zred[6]+zred[7];
    atomicAdd(&st[192], z);
  }
  // rvec partials: thread (g = tid>>6, d = tid&63) over 32 nodes
  {
    int gq = tid >> 6, d = tid & 63;
    float acc = 0.f;
    #pragma unroll 8
    for (int i = 0; i < 32; ++i){
      int nl = gq*32 + i;
      acc += wl[nl]*ob[nl*65 + d];
    }
    part[tid] = acc;
  }
  __syncthreads();
  if (tid < 64)
    atomicAdd(&st[128 + tid], part[tid] + part[64+tid] + part[128+tid] + part[192+tid]);
}

// ------------- head -------------
__global__ void k_z(const float* __restrict__ out, const float* __restrict__ st,
                    const int* __restrict__ nonring, float* __restrict__ z){
  int idx = blockIdx.x*256 + threadIdx.x;         // T*384 exact
  int t = idx / 384, c = idx % 384;
  float v;
  if (c < 256){
    int a = c*16 + (t >> 6);
    int node = nonring[a];
    v = out[(size_t)node*64 + (t & 63)];
  } else {
    int pi = t >> 3;                              // pool index (quirky repeat)
    v = (pi < 64) ? st[pi] : st[128 + (pi - 64)] / st[192];
  }
  z[idx] = v;
}

// memory LSTM cell batched 8 rows/block: hm = sig(go)*tanh(sig(gi)*tanh(gg))
__global__ void k_mem(const float* __restrict__ z, const float* __restrict__ wit,
                      const float* __restrict__ bi, const float* __restrict__ bh,
                      float* __restrict__ hm){
  __shared__ float zs[8][384];
  int j = threadIdx.x;             // 384
  int t0 = blockIdx.x * 8;         // grid 128 exact
  #pragma unroll
  for (int r = 0; r < 8; ++r) zs[r][j] = z[(size_t)(t0+r)*384 + j];
  __syncthreads();
  float gi[8], gg[8], go[8];
  #pragma unroll
  for (int r = 0; r < 8; ++r){
    gi[r] = bi[j]      + bh[j];
    gg[r] = bi[768+j]  + bh[768+j];
    go[r] = bi[1152+j] + bh[1152+j];
  }
  for (int k = 0; k < 384; ++k){
    const float* wr = wit + (size_t)k*1536;
    float wiv = wr[j], wgv = wr[768+j], wov = wr[1152+j];
    #pragma unroll
    for (int r = 0; r < 8; ++r){
      float zv = zs[r][k];
      gi[r] += zv*wiv; gg[r] += zv*wgv; go[r] += zv*wov;
    }
  }
  #pragma unroll
  for (int r = 0; r < 8; ++r){
    float cm = sigm(gi[r])*tanhf(gg[r]);
    hm[(size_t)(t0+r)*384 + j] = sigm(go[r])*tanhf(cm);
  }
}

__global__ void k_fin(const float* __restrict__ hm, const float* __restrict__ W1t,
                      const float* __restrict__ b1, const float* __restrict__ W2,
                      const float* __restrict__ b2, float* __restrict__ y){
  __shared__ float hsm[384];
  __shared__ float hid[128];
  int t = blockIdx.x, j = threadIdx.x;            // 128 threads
  hsm[j]     = hm[(size_t)t*384 + j];
  hsm[128+j] = hm[(size_t)t*384 + 128 + j];
  hsm[256+j] = hm[(size_t)t*384 + 256 + j];
  __syncthreads();
  float a = b1[j];
  for (int k = 0; k < 384; ++k) a += hsm[k]*W1t[k*128 + j];
  hid[j] = fmaxf(a, 0.0f);
  __syncthreads();
  if (j < 6){
    float acc = b2[j];
    #pragma unroll 8
    for (int k = 0; k < 128; ++k) acc += hid[k]*W2[j*128 + k];
    y[t*6 + j] = acc;
  }
}

extern "C" void kernel_launch(void* const* d_in, const int* in_sizes, int n_in,
                              void* d_out, int out_size, void* d_ws, size_t ws_size,
                              hipStream_t stream){
  const float* x      = (const float*)d_in[0];
  const float* ea     = (const float*)d_in[1];
  const float* W0     = (const float*)d_in[2];
  const float* b0     = (const float*)d_in[3];
  const float* We1    = (const float*)d_in[4];
  const float* be1    = (const float*)d_in[5];
  const float* We2    = (const float*)d_in[6];
  const float* be2    = (const float*)d_in[7];
  const float* root   = (const float*)d_in[8];
  const float* conv_b = (const float*)d_in[9];
  const float* gwih   = (const float*)d_in[10];
  const float* gwhh   = (const float*)d_in[11];
  const float* gbih   = (const float*)d_in[12];
  const float* gbhh   = (const float*)d_in[13];
  const float* s2swi  = (const float*)d_in[14];
  const float* s2swh  = (const float*)d_in[15];
  const float* s2sbi  = (const float*)d_in[16];
  const float* s2sbh  = (const float*)d_in[17];
  const float* memwi  = (const float*)d_in[18];
  const float* membi  = (const float*)d_in[20];
  const float* membh  = (const float*)d_in[21];
  const float* W1     = (const float*)d_in[22];
  const float* b1     = (const float*)d_in[23];
  const float* W2     = (const float*)d_in[24];
  const float* b2     = (const float*)d_in[25];
  const int*   eidx   = (const int*)d_in[26];
  const int*   nonr   = (const int*)d_in[27];
  const int* src = eidx, *dst = eidx + NE;
  float* y = (float*)d_out;

  char* wsb = (char*)d_ws;
  size_t off = 0;
  auto alloc = [&](size_t bytes){ size_t o = off; off += (bytes + 255) & ~(size_t)255; return o; };
  float* out    = (float*)(wsb + alloc((size_t)NN*64*4));
  float* h      = (float*)(wsb + alloc((size_t)NN*64*4));
  float* agg    = (float*)(wsb + alloc((size_t)NN*64*4));
  float* deg    = (float*)(wsb + alloc((size_t)NN*4));
  float* st     = (float*)(wsb + alloc(256*4));
  float* z      = (float*)(wsb + alloc((size_t)NT*384*4));
  float* hm     = (float*)(wsb + alloc((size_t)NT*384*4));
  float* memwit = (float*)(wsb + alloc((size_t)1536*384*4));
  float* W1t    = (float*)(wsb + alloc((size_t)128*384*4));
  float* gwih_t = (float*)(wsb + alloc((size_t)192*64*4));
  float* gwhh_t = (float*)(wsb + alloc((size_t)192*64*4));
  ushortT* Rbf  = (ushortT*)(wsb + alloc((size_t)NE*128*2));
  ushortT* We2bf= (ushortT*)(wsb + alloc((size_t)4096*128*2));
  (void)ws_size; (void)n_in; (void)in_sizes; (void)out_size;

  hipMemsetAsync(deg, 0, (size_t)NN*4, stream);
  hipMemsetAsync(st, 0, 256*4, stream);
  k_lin0<<<NN*64/256, 256, 0, stream>>>(x, W0, b0, out, h);
  k_deg<<<(NE+255)/256, 256, 0, stream>>>(dst, deg);
  k_invdeg<<<(NN+255)/256, 256, 0, stream>>>(deg);
  k_edgemlp<<<NE*128/256, 256, 0, stream>>>(ea, We1, be1, Rbf);
  k_cvt<<<(4096*128+255)/256, 256, 0, stream>>>(We2, We2bf, 4096*128);
  k_tr<<<(1536*384+255)/256, 256, 0, stream>>>(memwi, memwit, 1536, 384);
  k_tr<<<(128*384+255)/256, 256, 0, stream>>>(W1, W1t, 128, 384);
  k_tr<<<(192*64+255)/256, 256, 0, stream>>>(gwih, gwih_t, 192, 64);
  k_tr<<<(192*64+255)/256, 256, 0, stream>>>(gwhh, gwhh_t, 192, 64);

  for (int it = 0; it < 6; ++it){
    hipMemsetAsync(agg, 0, (size_t)NN*64*4, stream);
    k_fmsg<<<dim3((NE + EB - 1)/EB, 2), 256, 0, stream>>>(Rbf, We2bf, be2, out, src, dst, agg);
    k_gru<<<NN/16, 256, 0, stream>>>(agg, deg, root, conv_b, gwih_t, gwhh_t,
                                     gbih, gbhh, out, h);
  }

  for (int it = 0; it < 6; ++it){
    k_cell<<<1, 256, 0, stream>>>(s2swi, s2swh, s2sbi, s2sbh, st);
    k_s2s<<<(NN + 127)/128, 256, 0, stream>>>(out, st);
  }

  k_z<<<NT*384/256, 256, 0, stream>>>(out, st, nonr, z);
  k_mem<<<128, 384, 0, stream>>>(z, memwit, membi, membh, hm);
  k_fin<<<NT, 128, 0, stream>>>(hm, W1t, b1, W2, b2, y);
}

// Round 5
// 852.873 us; speedup vs baseline: 2.2110x; 1.1250x over previous
//
#include <hip/hip_runtime.h>
#include <hip/hip_bf16.h>

#define NN 20000
#define NE 60000
#define NT 1024

typedef unsigned short ushortT;
typedef __attribute__((ext_vector_type(8))) short bf16x8;
typedef __attribute__((ext_vector_type(4))) float f32x4;

__device__ __forceinline__ float sigm(float x){ return 1.0f/(1.0f+expf(-x)); }
__device__ __forceinline__ float bfu2f(ushortT u){ return __uint_as_float(((unsigned)u)<<16); }
__device__ __forceinline__ ushortT f2bfu(float f){
  __hip_bfloat16 b = __float2bfloat16(f);
  return *reinterpret_cast<ushortT*>(&b);
}

// ---------------- lin0: out = relu(x @ W0.T + b0); h = out ----------------
__global__ void k_lin0(const float* __restrict__ x, const float* __restrict__ W0,
                       const float* __restrict__ b0, float* __restrict__ out,
                       float* __restrict__ h){
  int idx = blockIdx.x*256 + threadIdx.x;       // N*64 exact
  int n = idx >> 6, j = idx & 63;
  float a = b0[j] + x[n*3+0]*W0[j*3+0] + x[n*3+1]*W0[j*3+1] + x[n*3+2]*W0[j*3+2];
  a = fmaxf(a, 0.0f);
  out[idx] = a; h[idx] = a;
}

__global__ void k_deg(const int* __restrict__ dst, float* __restrict__ deg){
  int e = blockIdx.x*256 + threadIdx.x;
  if (e < NE) atomicAdd(&deg[dst[e]], 1.0f);
}

// ------------- edge MLP hidden: R = relu(edge_attr @ We1.T + be1) (bf16) ----
__global__ void k_edgemlp(const float* __restrict__ ea, const float* __restrict__ We1,
                          const float* __restrict__ be1, ushortT* __restrict__ Rbf){
  int idx = blockIdx.x*256 + threadIdx.x;       // E*128 exact
  int e = idx >> 7, k = idx & 127;
  float a = be1[k];
  #pragma unroll
  for (int j = 0; j < 7; ++j) a += ea[e*7+j]*We1[k*7+j];
  Rbf[idx] = f2bfu(fmaxf(a, 0.0f));
}

// ------------- fused weight prep: bf16 cvts + GRU weight transposes -------------
// sec0: cvt We2 [4096*128]   sec1: cvt memwi [1536*384]   sec2: cvt W1 [128*384]
// sec3: tr gwih [192,64]     sec4: tr gwhh [192,64]
#define PREP_T ((4096*128) + (1536*384) + (128*384) + 2*(192*64))
__global__ void k_prep(const float* __restrict__ We2, const float* __restrict__ memwi,
                       const float* __restrict__ W1, const float* __restrict__ gwih,
                       const float* __restrict__ gwhh,
                       ushortT* __restrict__ We2bf, ushortT* __restrict__ wmem,
                       ushortT* __restrict__ w1bf, float* __restrict__ gwih_t,
                       float* __restrict__ gwhh_t){
  int idx = blockIdx.x*256 + threadIdx.x;
  if (idx < 4096*128){ We2bf[idx] = f2bfu(We2[idx]); return; }
  idx -= 4096*128;
  if (idx < 1536*384){ wmem[idx] = f2bfu(memwi[idx]); return; }
  idx -= 1536*384;
  if (idx < 128*384){ w1bf[idx] = f2bfu(W1[idx]); return; }
  idx -= 128*384;
  if (idx < 192*64){ int r = idx / 64, c = idx % 64; gwih_t[c*192 + r] = gwih[idx]; return; }
  idx -= 192*64;
  if (idx < 192*64){ int r = idx / 64, c = idx % 64; gwhh_t[c*192 + r] = gwhh[idx]; return; }
}

// ---------- fused NNConv message: agg[dst[e]] += out[src[e]] @ (R[e]@We2^T + be2) ----------
#define EB 256
__global__ __launch_bounds__(256, 3) void k_fmsg(
    const ushortT* __restrict__ Rbf, const ushortT* __restrict__ We2bf,
    const float* __restrict__ be2, const float* __restrict__ out,
    const int* __restrict__ src, const int* __restrict__ dst,
    float* __restrict__ agg)
{
  __shared__ ushortT o_sT[64][EB+8];   // bf16 out[src[e]] transposed [d][edge]
  __shared__ ushortT bufB[2][4096];    // 32 rows x 128 k bf16 (8KB each), swizzled slots
  __shared__ int dst_s[EB];

  int tid = threadIdx.x;
  int e0 = blockIdx.x * EB;
  int fh = blockIdx.y;                 // 0..1
  int w = tid >> 6, lane = tid & 63;
  int l15 = lane & 15, g = lane >> 4;  // g in 0..3

  // ---- prologue: dst + o gather (bf16, transposed) ----
  {
    int ge = e0 + tid;
    int sn = (ge < NE) ? src[ge] : -1;
    dst_s[tid] = (ge < NE) ? dst[ge] : -1;
    const float* op = out + (size_t)((sn < 0) ? 0 : sn)*64;
    #pragma unroll
    for (int i = 0; i < 16; ++i){
      float4 v = make_float4(0.f,0.f,0.f,0.f);
      if (sn >= 0) v = *reinterpret_cast<const float4*>(op + i*4);
      o_sT[i*4+0][tid] = f2bfu(v.x);
      o_sT[i*4+1][tid] = f2bfu(v.y);
      o_sT[i*4+2][tid] = f2bfu(v.z);
      o_sT[i*4+3][tid] = f2bfu(v.w);
    }
  }
  // stage B tile for d=0 (2 global_load_lds per wave; linear LDS, pre-swizzled source)
  #pragma unroll
  for (int i = 0; i < 2; ++i){
    int s = (w*2 + i)*64 + lane;          // 0..511
    int row = s >> 4, kslot = s & 15;
    const ushortT* gp = We2bf + (size_t)(fh*32 + row)*128 + ((kslot ^ (row & 7))<<3);
    __builtin_amdgcn_global_load_lds(
        (const __attribute__((address_space(1))) void*)gp,
        (__attribute__((address_space(3))) void*)&bufB[0][(size_t)s*8], 16, 0, 0);
  }

  // A fragments: R rows for this wave's 64 edges, all K=128 (4 k-steps)
  bf16x8 af[4][4];
  #pragma unroll
  for (int t = 0; t < 4; ++t){
    #pragma unroll
    for (int ks = 0; ks < 4; ++ks){
      int ge = e0 + w*64 + t*16 + l15;
      bf16x8 z = {0,0,0,0,0,0,0,0};
      af[t][ks] = (ge < NE) ? *reinterpret_cast<const bf16x8*>(Rbf + (size_t)ge*128 + ks*32 + g*8) : z;
    }
  }

  f32x4 msg[4][2];
  #pragma unroll
  for (int t = 0; t < 4; ++t){
    #pragma unroll
    for (int q = 0; q < 2; ++q){ msg[t][q][0]=0.f; msg[t][q][1]=0.f; msg[t][q][2]=0.f; msg[t][q][3]=0.f; }
  }
  __syncthreads();   // tile 0 staged (barrier drains vmcnt), o_sT ready

  for (int d = 0; d < 64; ++d){
    int cur = d & 1;
    if (d < 63){
      #pragma unroll
      for (int i = 0; i < 2; ++i){
        int s = (w*2 + i)*64 + lane;
        int row = s >> 4, kslot = s & 15;
        const ushortT* gp = We2bf + (size_t)((d+1)*64 + fh*32 + row)*128 + ((kslot ^ (row & 7))<<3);
        __builtin_amdgcn_global_load_lds(
            (const __attribute__((address_space(1))) void*)gp,
            (__attribute__((address_space(3))) void*)&bufB[cur^1][(size_t)s*8], 16, 0, 0);
      }
    }
    // MFMA: ks-inner B loads to bound register liveness
    f32x4 ac[4][2];
    #pragma unroll
    for (int t = 0; t < 4; ++t){
      #pragma unroll
      for (int q = 0; q < 2; ++q){ ac[t][q][0]=0.f; ac[t][q][1]=0.f; ac[t][q][2]=0.f; ac[t][q][3]=0.f; }
    }
    #pragma unroll
    for (int ks = 0; ks < 4; ++ks){
      bf16x8 b0 = *reinterpret_cast<const bf16x8*>(&bufB[cur][ (l15)*128      + ((((ks<<2)+g) ^ (l15&7))<<3) ]);
      bf16x8 b1 = *reinterpret_cast<const bf16x8*>(&bufB[cur][ (16+l15)*128   + ((((ks<<2)+g) ^ (l15&7))<<3) ]);
      #pragma unroll
      for (int t = 0; t < 4; ++t){
        ac[t][0] = __builtin_amdgcn_mfma_f32_16x16x32_bf16(af[t][ks], b0, ac[t][0], 0, 0, 0);
        ac[t][1] = __builtin_amdgcn_mfma_f32_16x16x32_bf16(af[t][ks], b1, ac[t][1], 0, 0, 0);
      }
    }
    float be2v0 = be2[d*64 + fh*32 + l15];
    float be2v1 = be2[d*64 + fh*32 + 16 + l15];
    #pragma unroll
    for (int t = 0; t < 4; ++t){
      ushort4 ou = *reinterpret_cast<const ushort4*>(&o_sT[d][w*64 + t*16 + g*4]);
      float o0 = bfu2f(ou.x), o1 = bfu2f(ou.y), o2 = bfu2f(ou.z), o3 = bfu2f(ou.w);
      msg[t][0][0] += o0*(ac[t][0][0] + be2v0);
      msg[t][0][1] += o1*(ac[t][0][1] + be2v0);
      msg[t][0][2] += o2*(ac[t][0][2] + be2v0);
      msg[t][0][3] += o3*(ac[t][0][3] + be2v0);
      msg[t][1][0] += o0*(ac[t][1][0] + be2v1);
      msg[t][1][1] += o1*(ac[t][1][1] + be2v1);
      msg[t][1][2] += o2*(ac[t][1][2] + be2v1);
      msg[t][1][3] += o3*(ac[t][1][3] + be2v1);
    }
    __syncthreads();   // tile d+1 ready; all reads of bufB[cur] done
  }

  #pragma unroll
  for (int t = 0; t < 4; ++t){
    #pragma unroll
    for (int r = 0; r < 4; ++r){
      int el = w*64 + t*16 + g*4 + r;
      int tn = dst_s[el];
      if (tn >= 0){
        atomicAdd(&agg[(size_t)tn*64 + fh*32 + l15],      msg[t][0][r]);
        atomicAdd(&agg[(size_t)tn*64 + fh*32 + 16 + l15], msg[t][1][r]);
      }
    }
  }
}

// ------------- NNConv epilogue + GRU cell (16 nodes / block, 4 per thread) ----------------
// also zeroes agg for the next iteration (saves per-iter memset)
__global__ void k_gru(const float* __restrict__ agg_in, const float* __restrict__ deg,
                      const float* __restrict__ root, const float* __restrict__ conv_b,
                      const float* __restrict__ wih_t, const float* __restrict__ whh_t,
                      const float* __restrict__ bih, const float* __restrict__ bhh,
                      float* __restrict__ out, float* __restrict__ h){
  __shared__ float os[16][64], hsm[16][64], ms[16][64];
  float* agg = const_cast<float*>(agg_in);
  int tid = threadIdx.x;
  int j = tid & 63, sub = tid >> 6;   // sub 0..3
  int n0 = blockIdx.x * 16;
  #pragma unroll
  for (int i = 0; i < 4; ++i){
    int nl = sub + 4*i;
    os[nl][j]  = out[(size_t)(n0+nl)*64 + j];
    hsm[nl][j] = h[(size_t)(n0+nl)*64 + j];
  }
  __syncthreads();
  float a[4];
  #pragma unroll
  for (int i = 0; i < 4; ++i){
    int nl = sub + 4*i;
    float inv = 1.0f/fmaxf(deg[n0+nl], 1.0f);
    a[i] = agg[(size_t)(n0+nl)*64 + j]*inv + conv_b[j];
    agg[(size_t)(n0+nl)*64 + j] = 0.0f;     // re-zero for next iteration
  }
  for (int d = 0; d < 64; ++d){
    float rdj = root[d*64 + j];
    #pragma unroll
    for (int i = 0; i < 4; ++i) a[i] += os[sub + 4*i][d]*rdj;
  }
  #pragma unroll
  for (int i = 0; i < 4; ++i) ms[sub + 4*i][j] = fmaxf(a[i], 0.0f);
  __syncthreads();
  float gxr[4], gxz[4], gxn[4], ghr[4], ghz[4], ghn[4];
  #pragma unroll
  for (int i = 0; i < 4; ++i){
    gxr[i] = bih[j];     gxz[i] = bih[64+j];  gxn[i] = bih[128+j];
    ghr[i] = bhh[j];     ghz[i] = bhh[64+j];  ghn[i] = bhh[128+j];
  }
  for (int d = 0; d < 64; ++d){
    float wir = wih_t[d*192 + j], wiz = wih_t[d*192 + 64 + j], win = wih_t[d*192 + 128 + j];
    float whr = whh_t[d*192 + j], whz = whh_t[d*192 + 64 + j], whn = whh_t[d*192 + 128 + j];
    #pragma unroll
    for (int i = 0; i < 4; ++i){
      float mv = ms[sub + 4*i][d], hv = hsm[sub + 4*i][d];
      gxr[i] += mv*wir; gxz[i] += mv*wiz; gxn[i] += mv*win;
      ghr[i] += hv*whr; ghz[i] += hv*whz; ghn[i] += hv*whn;
    }
  }
  #pragma unroll
  for (int i = 0; i < 4; ++i){
    int nl = sub + 4*i;
    float r = sigm(gxr[i]+ghr[i]), zg = sigm(gxz[i]+ghz[i]);
    float nn_ = tanhf(gxn[i] + r*ghn[i]);
    float hn = (1.0f - zg)*nn_ + zg*hsm[nl][j];
    h[(size_t)(n0+nl)*64 + j]   = hn;
    out[(size_t)(n0+nl)*64 + j] = hn;
  }
}

// ------------- Set2Set -------------
// st layout (floats): hs[0..64) cs[64..128) rvec[128..192) Z@192
__global__ void k_cell(const float* __restrict__ wi, const float* __restrict__ wh,
                       const float* __restrict__ bi, const float* __restrict__ bh,
                       float* __restrict__ st){
  __shared__ float qs[128], hsl[64], g[256];
  int j = threadIdx.x;   // 256
  if (j < 64){ qs[j] = st[j]; hsl[j] = st[j]; }
  else if (j < 128){
    float Z = st[192];
    qs[j] = (Z != 0.0f) ? st[128 + (j-64)]/Z : 0.0f;
  }
  __syncthreads();
  float a = bi[j] + bh[j];
  #pragma unroll 8
  for (int k = 0; k < 128; ++k) a += qs[k]*wi[j*128 + k];
  #pragma unroll 8
  for (int k = 0; k < 64;  ++k) a += hsl[k]*wh[j*64 + k];
  g[j] = a;
  __syncthreads();
  if (j < 64){
    float iv = sigm(g[j]), fv = sigm(g[64+j]);
    float gv = tanhf(g[128+j]), ov = sigm(g[192+j]);
    float c = fv*st[64+j] + iv*gv;
    st[64+j] = c;
    st[j] = ov*tanhf(c);
  } else if (j < 128){
    st[128 + (j-64)] = 0.0f;    // zero rvec accumulator
  } else if (j == 128){
    st[192] = 0.0f;             // zero Z
  }
}

// fused attention: e = out@hs, w = exp(e) (no max needed, |e|<=64), Z += sum w, rvec += w*out
__global__ void k_s2s(const float* __restrict__ out, float* __restrict__ st){
  __shared__ float ob[128*65];
  __shared__ float wl[128], zred[128], hsl[64], part[256];
  int tid = threadIdx.x;      // 256
  int n0 = blockIdx.x * 128;
  if (tid < 64) hsl[tid] = st[tid];
  #pragma unroll
  for (int rr = 0; rr < 8; ++rr){
    int idx = rr*1024 + tid*4;
    int nl = idx >> 6, jj = idx & 63;
    float4 v = make_float4(0.f,0.f,0.f,0.f);
    if (n0 + nl < NN) v = *reinterpret_cast<const float4*>(&out[(size_t)(n0+nl)*64 + jj]);
    ob[nl*65 + jj + 0] = v.x; ob[nl*65 + jj + 1] = v.y;
    ob[nl*65 + jj + 2] = v.z; ob[nl*65 + jj + 3] = v.w;
  }
  __syncthreads();
  if (tid < 128){
    float e = 0.f;
    #pragma unroll 8
    for (int jj = 0; jj < 64; ++jj) e += ob[tid*65 + jj]*hsl[jj];
    float wv = (n0 + tid < NN) ? expf(e) : 0.f;
    wl[tid] = wv; zred[tid] = wv;
  }
  __syncthreads();
  if (tid < 64) zred[tid] += zred[tid + 64];
  __syncthreads();
  if (tid < 32) zred[tid] += zred[tid + 32];
  __syncthreads();
  if (tid < 16) zred[tid] += zred[tid + 16];
  __syncthreads();
  if (tid < 8) zred[tid] += zred[tid + 8];
  __syncthreads();
  if (tid == 0){
    float z = zred[0]+zred[1]+zred[2]+zred[3]+zred[4]+zred[5]+zred[6]+zred[7];
    atomicAdd(&st[192], z);
  }
  {
    int gq = tid >> 6, d = tid & 63;
    float acc = 0.f;
    #pragma unroll 8
    for (int i = 0; i < 32; ++i){
      int nl = gq*32 + i;
      acc += wl[nl]*ob[nl*65 + d];
    }
    part[tid] = acc;
  }
  __syncthreads();
  if (tid < 64)
    atomicAdd(&st[128 + tid], part[tid] + part[64+tid] + part[128+tid] + part[192+tid]);
}

// ------------- head -------------
// z_in (bf16): [T, 384]; cols 0..255 gather from out, cols 256..383 = pool repeat
__global__ void k_z(const float* __restrict__ out, const float* __restrict__ st,
                    const int* __restrict__ nonring, ushortT* __restrict__ zbf){
  int idx = blockIdx.x*256 + threadIdx.x;         // T*384 exact
  int t = idx / 384, c = idx % 384;
  float v;
  if (c < 256){
    int a = c*16 + (t >> 6);
    int node = nonring[a];
    v = out[(size_t)node*64 + (t & 63)];
  } else {
    int pi = t >> 3;                              // pool index (quirky repeat)
    v = (pi < 64) ? st[pi] : st[128 + (pi - 64)] / st[192];
  }
  zbf[idx] = f2bfu(v);
}

// memory LSTM via MFMA: gates = zbf @ wmem^T (+biases); hm = sig(o)*tanh(sig(i)*tanh(g))
// grid (32, 6): m0 = bx*32 (rows t), j0 = by*64; wave w -> j-subtile j0 + w*16
__global__ __launch_bounds__(256) void k_mem2(
    const ushortT* __restrict__ zbf, const ushortT* __restrict__ wmem,
    const float* __restrict__ membi, const float* __restrict__ membh,
    ushortT* __restrict__ hmbf){
  int tid = threadIdx.x;
  int w = tid >> 6, lane = tid & 63;
  int l15 = lane & 15, g = lane >> 4;
  int m0 = blockIdx.x * 32;
  int jw = blockIdx.y * 64 + w * 16;

  f32x4 ai[2], ag[2], ao[2];
  #pragma unroll
  for (int m = 0; m < 2; ++m){
    #pragma unroll
    for (int r = 0; r < 4; ++r){ ai[m][r]=0.f; ag[m][r]=0.f; ao[m][r]=0.f; }
  }
  const ushortT* a0p = zbf + (size_t)(m0 + l15)*384 + g*8;
  const ushortT* a1p = zbf + (size_t)(m0 + 16 + l15)*384 + g*8;
  const ushortT* bip = wmem + (size_t)(jw + l15)*384 + g*8;
  const ushortT* bgp = wmem + (size_t)(768 + jw + l15)*384 + g*8;
  const ushortT* bop = wmem + (size_t)(1152 + jw + l15)*384 + g*8;
  #pragma unroll
  for (int ks = 0; ks < 12; ++ks){
    bf16x8 a0 = *reinterpret_cast<const bf16x8*>(a0p + ks*32);
    bf16x8 a1 = *reinterpret_cast<const bf16x8*>(a1p + ks*32);
    bf16x8 bi = *reinterpret_cast<const bf16x8*>(bip + ks*32);
    bf16x8 bg = *reinterpret_cast<const bf16x8*>(bgp + ks*32);
    bf16x8 bo = *reinterpret_cast<const bf16x8*>(bop + ks*32);
    ai[0] = __builtin_amdgcn_mfma_f32_16x16x32_bf16(a0, bi, ai[0], 0, 0, 0);
    ai[1] = __builtin_amdgcn_mfma_f32_16x16x32_bf16(a1, bi, ai[1], 0, 0, 0);
    ag[0] = __builtin_amdgcn_mfma_f32_16x16x32_bf16(a0, bg, ag[0], 0, 0, 0);
    ag[1] = __builtin_amdgcn_mfma_f32_16x16x32_bf16(a1, bg, ag[1], 0, 0, 0);
    ao[0] = __builtin_amdgcn_mfma_f32_16x16x32_bf16(a0, bo, ao[0], 0, 0, 0);
    ao[1] = __builtin_amdgcn_mfma_f32_16x16x32_bf16(a1, bo, ao[1], 0, 0, 0);
  }
  int j = jw + l15;
  float bI = membi[j]        + membh[j];
  float bG = membi[768 + j]  + membh[768 + j];
  float bO = membi[1152 + j] + membh[1152 + j];
  #pragma unroll
  for (int m = 0; m < 2; ++m){
    #pragma unroll
    for (int r = 0; r < 4; ++r){
      int t = m0 + m*16 + g*4 + r;
      float gi = ai[m][r] + bI;
      float gg = ag[m][r] + bG;
      float go = ao[m][r] + bO;
      float cm = sigm(gi)*tanhf(gg);
      hmbf[(size_t)t*384 + j] = f2bfu(sigm(go)*tanhf(cm));
    }
  }
}

// fin stage 1 via MFMA: hid = relu(hm @ W1^T + b1)  [1024 x 128] f32
// grid (32, 2): m0 = bx*32, c0 = by*64 + w*16
__global__ __launch_bounds__(256) void k_fin1(
    const ushortT* __restrict__ hmbf, const ushortT* __restrict__ w1bf,
    const float* __restrict__ b1, float* __restrict__ hid){
  int tid = threadIdx.x;
  int w = tid >> 6, lane = tid & 63;
  int l15 = lane & 15, g = lane >> 4;
  int m0 = blockIdx.x * 32;
  int cw = blockIdx.y * 64 + w * 16;

  f32x4 acc[2];
  #pragma unroll
  for (int m = 0; m < 2; ++m){
    #pragma unroll
    for (int r = 0; r < 4; ++r) acc[m][r] = 0.f;
  }
  const ushortT* a0p = hmbf + (size_t)(m0 + l15)*384 + g*8;
  const ushortT* a1p = hmbf + (size_t)(m0 + 16 + l15)*384 + g*8;
  const ushortT* bp  = w1bf + (size_t)(cw + l15)*384 + g*8;
  #pragma unroll
  for (int ks = 0; ks < 12; ++ks){
    bf16x8 a0 = *reinterpret_cast<const bf16x8*>(a0p + ks*32);
    bf16x8 a1 = *reinterpret_cast<const bf16x8*>(a1p + ks*32);
    bf16x8 b  = *reinterpret_cast<const bf16x8*>(bp + ks*32);
    acc[0] = __builtin_amdgcn_mfma_f32_16x16x32_bf16(a0, b, acc[0], 0, 0, 0);
    acc[1] = __builtin_amdgcn_mfma_f32_16x16x32_bf16(a1, b, acc[1], 0, 0, 0);
  }
  int c = cw + l15;
  float bv = b1[c];
  #pragma unroll
  for (int m = 0; m < 2; ++m){
    #pragma unroll
    for (int r = 0; r < 4; ++r){
      int t = m0 + m*16 + g*4 + r;
      hid[(size_t)t*128 + c] = fmaxf(acc[m][r] + bv, 0.0f);
    }
  }
}

// fin stage 2: y[t][j] = b2[j] + hid[t] . W2[j]   (j < 6)
__global__ void k_fin2(const float* __restrict__ hid, const float* __restrict__ W2,
                       const float* __restrict__ b2, float* __restrict__ y){
  int tid = threadIdx.x;                 // 256
  int t = blockIdx.x*32 + (tid >> 3);    // grid 32 exact
  int j = tid & 7;
  if (j >= 6) return;
  float a = b2[j];
  const float* hp = hid + (size_t)t*128;
  const float* wp = W2 + j*128;
  #pragma unroll 8
  for (int k = 0; k < 128; ++k) a += hp[k]*wp[k];
  y[t*6 + j] = a;
}

extern "C" void kernel_launch(void* const* d_in, const int* in_sizes, int n_in,
                              void* d_out, int out_size, void* d_ws, size_t ws_size,
                              hipStream_t stream){
  const float* x      = (const float*)d_in[0];
  const float* ea     = (const float*)d_in[1];
  const float* W0     = (const float*)d_in[2];
  const float* b0     = (const float*)d_in[3];
  const float* We1    = (const float*)d_in[4];
  const float* be1    = (const float*)d_in[5];
  const float* We2    = (const float*)d_in[6];
  const float* be2    = (const float*)d_in[7];
  const float* root   = (const float*)d_in[8];
  const float* conv_b = (const float*)d_in[9];
  const float* gwih   = (const float*)d_in[10];
  const float* gwhh   = (const float*)d_in[11];
  const float* gbih   = (const float*)d_in[12];
  const float* gbhh   = (const float*)d_in[13];
  const float* s2swi  = (const float*)d_in[14];
  const float* s2swh  = (const float*)d_in[15];
  const float* s2sbi  = (const float*)d_in[16];
  const float* s2sbh  = (const float*)d_in[17];
  const float* memwi  = (const float*)d_in[18];
  const float* membi  = (const float*)d_in[20];
  const float* membh  = (const float*)d_in[21];
  const float* W1     = (const float*)d_in[22];
  const float* b1     = (const float*)d_in[23];
  const float* W2     = (const float*)d_in[24];
  const float* b2     = (const float*)d_in[25];
  const int*   eidx   = (const int*)d_in[26];
  const int*   nonr   = (const int*)d_in[27];
  const int* src = eidx, *dst = eidx + NE;
  float* y = (float*)d_out;

  char* wsb = (char*)d_ws;
  size_t off = 0;
  auto alloc = [&](size_t bytes){ size_t o = off; off += (bytes + 255) & ~(size_t)255; return o; };
  float* out    = (float*)(wsb + alloc((size_t)NN*64*4));
  float* h      = (float*)(wsb + alloc((size_t)NN*64*4));
  float* agg    = (float*)(wsb + alloc((size_t)NN*64*4));
  float* deg    = (float*)(wsb + alloc((size_t)NN*4));
  float* st     = (float*)(wsb + alloc(256*4));
  float* hid    = (float*)(wsb + alloc((size_t)NT*128*4));
  float* gwih_t = (float*)(wsb + alloc((size_t)192*64*4));
  float* gwhh_t = (float*)(wsb + alloc((size_t)192*64*4));
  ushortT* Rbf  = (ushortT*)(wsb + alloc((size_t)NE*128*2));
  ushortT* We2bf= (ushortT*)(wsb + alloc((size_t)4096*128*2));
  ushortT* wmem = (ushortT*)(wsb + alloc((size_t)1536*384*2));
  ushortT* w1bf = (ushortT*)(wsb + alloc((size_t)128*384*2));
  ushortT* zbf  = (ushortT*)(wsb + alloc((size_t)NT*384*2));
  ushortT* hmbf = (ushortT*)(wsb + alloc((size_t)NT*384*2));
  (void)ws_size; (void)n_in; (void)in_sizes; (void)out_size;

  hipMemsetAsync(deg, 0, (size_t)NN*4, stream);
  hipMemsetAsync(st, 0, 256*4, stream);
  hipMemsetAsync(agg, 0, (size_t)NN*64*4, stream);
  k_lin0<<<NN*64/256, 256, 0, stream>>>(x, W0, b0, out, h);
  k_deg<<<(NE+255)/256, 256, 0, stream>>>(dst, deg);
  k_edgemlp<<<NE*128/256, 256, 0, stream>>>(ea, We1, be1, Rbf);
  k_prep<<<(PREP_T+255)/256, 256, 0, stream>>>(We2, memwi, W1, gwih, gwhh,
                                               We2bf, wmem, w1bf, gwih_t, gwhh_t);

  for (int it = 0; it < 6; ++it){
    k_fmsg<<<dim3((NE + EB - 1)/EB, 2), 256, 0, stream>>>(Rbf, We2bf, be2, out, src, dst, agg);
    k_gru<<<NN/16, 256, 0, stream>>>(agg, deg, root, conv_b, gwih_t, gwhh_t,
                                     gbih, gbhh, out, h);
  }

  for (int it = 0; it < 6; ++it){
    k_cell<<<1, 256, 0, stream>>>(s2swi, s2swh, s2sbi, s2sbh, st);
    k_s2s<<<(NN + 127)/128, 256, 0, stream>>>(out, st);
  }

  k_z<<<NT*384/256, 256, 0, stream>>>(out, st, nonr, zbf);
  k_mem2<<<dim3(32, 6), 256, 0, stream>>>(zbf, wmem, membi, membh, hmbf);
  k_fin1<<<dim3(32, 2), 256, 0, stream>>>(hmbf, w1bf, b1, hid);
  k_fin2<<<32, 256, 0, stream>>>(hid, W2, b2, y);
}